// Round 1
// baseline (1051.939 us; speedup 1.0000x reference)
//
#include <hip/hip_runtime.h>

#define NUM_USERS 100000
#define NUM_ITEMS 50000
#define NUM_EDGES 4000000
#define DIM 64

// Source-table slicing: 1<<14 = 16384 rows/slice = 2 MB bf16 per slice.
#define SLICE_SHIFT 14
#define SLICES_U ((NUM_USERS + (1 << SLICE_SHIFT) - 1) >> SLICE_SHIFT)  // 7
#define SLICES_I ((NUM_ITEMS + (1 << SLICE_SHIFT) - 1) >> SLICE_SHIFT)  // 4

#define SCAN_NB 512
#define SCAN_THREADS 256

// Padded-bin capacity: 48 recs = 192 B = 3 cache lines per bin.
// P(Poisson(11.4) >= 48) ~ 1e-14/bin -> no overflow across 750K bins; gather
// clamps len<=C anyway.
#define PAD_CAP 48

// Packed CSR record: (src_row << 15) | w_quant15 (err <= 1.5e-5 << bf16 noise).
#define W_SCALE 32767.0f
#define W_INV   (1.0f / 32767.0f)

// ---------------- fallback: scatter-atomic (round-1 kernel) ----------------
__global__ __launch_bounds__(256) void lightgcn_scatter(
    const float* __restrict__ user_emb,
    const float* __restrict__ item_emb,
    const float* __restrict__ edge_norm,
    const int* __restrict__ u_idx,
    const int* __restrict__ i_idx,
    float* __restrict__ agg_users,
    float* __restrict__ agg_items)
{
    long long gid = (long long)blockIdx.x * blockDim.x + threadIdx.x;
    int edge = (int)(gid >> 6);
    int lane = (int)(gid & 63);
    if (edge >= NUM_EDGES) return;
    int u = u_idx[edge];
    int i = i_idx[edge];
    float n = edge_norm[edge];
    float uval = user_emb[(size_t)u * DIM + lane];
    float ival = item_emb[(size_t)i * DIM + lane];
    atomicAdd(&agg_items[(size_t)i * DIM + lane], n * uval);
    atomicAdd(&agg_users[(size_t)u * DIM + lane], n * ival);
}

// ---------------- bf16 conversion of BOTH embedding tables (one launch) ----
__global__ __launch_bounds__(256) void convert_both(
    const float4* __restrict__ usrc, const float4* __restrict__ isrc,
    ushort4* __restrict__ udst, ushort4* __restrict__ idst,
    int un4, int in4)
{
    int t = blockIdx.x * blockDim.x + threadIdx.x;
    const float4* s; ushort4* d; int idx;
    if (t < un4) { s = usrc; d = udst; idx = t; }
    else if (t < un4 + in4) { s = isrc; d = idst; idx = t - un4; }
    else return;
    float4 v = s[idx];
    ushort4 o;
    uint b;
    b = __float_as_uint(v.x); o.x = (ushort)((b + 0x7FFFu + ((b >> 16) & 1u)) >> 16);
    b = __float_as_uint(v.y); o.y = (ushort)((b + 0x7FFFu + ((b >> 16) & 1u)) >> 16);
    b = __float_as_uint(v.z); o.z = (ushort)((b + 0x7FFFu + ((b >> 16) & 1u)) >> 16);
    b = __float_as_uint(v.w); o.w = (ushort)((b + 0x7FFFu + ((b >> 16) & 1u)) >> 16);
    d[idx] = o;
}

// ---------------- FUSED rank + padded scatter (tier 1) ----------------------
// Tier 1 needs no scan between ranking and scattering (pos = bin*PAD_CAP+rank),
// so the atomicAdd that produces the rank can directly feed the record store.
// This removes a full 4M-edge pass (rank write 16MB + rank read 16MB +
// idx/norm re-read 48MB) vs the old rank_both + scatter_pad pair.
// All 8 atomics are issued before any dependent store so the compiler can keep
// 8 RMWs in flight per thread; the scattered rec stores drain in the shadow of
// the atomic-RMW wall (which is the measured bottleneck, ~25.5 G atomics/s).
__global__ __launch_bounds__(256) void rank_scatter_pad(
    const int4* __restrict__ u4, const int4* __restrict__ i4,
    const float4* __restrict__ n4,
    int* __restrict__ cnt, int n_i, int su_shift, int si_shift,
    uint* __restrict__ rec)
{
    int t = blockIdx.x * blockDim.x + threadIdx.x;
    if (t >= NUM_EDGES / 4) return;
    int4   u = u4[t];
    int4   i = i4[t];
    float4 n = n4[t];

    uint w0 = (uint)(n.x * W_SCALE + 0.5f); if (w0 > 32767u) w0 = 32767u;
    uint w1 = (uint)(n.y * W_SCALE + 0.5f); if (w1 > 32767u) w1 = 32767u;
    uint w2 = (uint)(n.z * W_SCALE + 0.5f); if (w2 > 32767u) w2 = 32767u;
    uint w3 = (uint)(n.w * W_SCALE + 0.5f); if (w3 > 32767u) w3 = 32767u;

    int bi0 = (u.x >> su_shift) * NUM_ITEMS + i.x;
    int bi1 = (u.y >> su_shift) * NUM_ITEMS + i.y;
    int bi2 = (u.z >> su_shift) * NUM_ITEMS + i.z;
    int bi3 = (u.w >> su_shift) * NUM_ITEMS + i.w;
    int bu0 = n_i + (i.x >> si_shift) * NUM_USERS + u.x;
    int bu1 = n_i + (i.y >> si_shift) * NUM_USERS + u.y;
    int bu2 = n_i + (i.z >> si_shift) * NUM_USERS + u.z;
    int bu3 = n_i + (i.w >> si_shift) * NUM_USERS + u.w;

    // 8 independent atomics issued together.
    int ri0 = atomicAdd(&cnt[bi0], 1);
    int ri1 = atomicAdd(&cnt[bi1], 1);
    int ri2 = atomicAdd(&cnt[bi2], 1);
    int ri3 = atomicAdd(&cnt[bi3], 1);
    int ru0 = atomicAdd(&cnt[bu0], 1);
    int ru1 = atomicAdd(&cnt[bu1], 1);
    int ru2 = atomicAdd(&cnt[bu2], 1);
    int ru3 = atomicAdd(&cnt[bu3], 1);

    // Dependent stores.
    if (ri0 < PAD_CAP) rec[(size_t)bi0 * PAD_CAP + ri0] = ((uint)u.x << 15) | w0;
    if (ri1 < PAD_CAP) rec[(size_t)bi1 * PAD_CAP + ri1] = ((uint)u.y << 15) | w1;
    if (ri2 < PAD_CAP) rec[(size_t)bi2 * PAD_CAP + ri2] = ((uint)u.z << 15) | w2;
    if (ri3 < PAD_CAP) rec[(size_t)bi3 * PAD_CAP + ri3] = ((uint)u.w << 15) | w3;
    if (ru0 < PAD_CAP) rec[(size_t)bu0 * PAD_CAP + ru0] = ((uint)i.x << 15) | w0;
    if (ru1 < PAD_CAP) rec[(size_t)bu1 * PAD_CAP + ru1] = ((uint)i.y << 15) | w1;
    if (ru2 < PAD_CAP) rec[(size_t)bu2 * PAD_CAP + ru2] = ((uint)i.z << 15) | w2;
    if (ru3 < PAD_CAP) rec[(size_t)bu3 * PAD_CAP + ru3] = ((uint)i.w << 15) | w3;
}

// ---------------- padded gather: one 64-lane wave per dst row ---------------
__global__ __launch_bounds__(256) void gather_pad(
    const int* __restrict__ cnt, int bin_base,
    const uint* __restrict__ rec,
    const ushort* __restrict__ emb16,
    float* __restrict__ out, int nrows, int accumulate)
{
    int gid  = blockIdx.x * blockDim.x + threadIdx.x;
    int row  = gid >> 6;
    int lane = gid & 63;
    if (row >= nrows) return;
    int b = bin_base + row;
    int len = cnt[b];
    if (len > PAD_CAP) len = PAD_CAP;
    size_t s = (size_t)b * PAD_CAP;
    size_t e = s + len;
    float acc = accumulate ? out[(size_t)row * DIM + lane] : 0.f;
    size_t k = s;
    for (; k + 8 <= e; k += 8) {
        uint r0 = rec[k],   r1 = rec[k+1], r2 = rec[k+2], r3 = rec[k+3];
        uint r4 = rec[k+4], r5 = rec[k+5], r6 = rec[k+6], r7 = rec[k+7];
        ushort b0 = emb16[(size_t)(r0 >> 15) * DIM + lane];
        ushort b1 = emb16[(size_t)(r1 >> 15) * DIM + lane];
        ushort b2 = emb16[(size_t)(r2 >> 15) * DIM + lane];
        ushort b3 = emb16[(size_t)(r3 >> 15) * DIM + lane];
        ushort b4 = emb16[(size_t)(r4 >> 15) * DIM + lane];
        ushort b5 = emb16[(size_t)(r5 >> 15) * DIM + lane];
        ushort b6 = emb16[(size_t)(r6 >> 15) * DIM + lane];
        ushort b7 = emb16[(size_t)(r7 >> 15) * DIM + lane];
        acc += (float)(r0 & 0x7FFFu) * W_INV * __uint_as_float((uint)b0 << 16);
        acc += (float)(r1 & 0x7FFFu) * W_INV * __uint_as_float((uint)b1 << 16);
        acc += (float)(r2 & 0x7FFFu) * W_INV * __uint_as_float((uint)b2 << 16);
        acc += (float)(r3 & 0x7FFFu) * W_INV * __uint_as_float((uint)b3 << 16);
        acc += (float)(r4 & 0x7FFFu) * W_INV * __uint_as_float((uint)b4 << 16);
        acc += (float)(r5 & 0x7FFFu) * W_INV * __uint_as_float((uint)b5 << 16);
        acc += (float)(r6 & 0x7FFFu) * W_INV * __uint_as_float((uint)b6 << 16);
        acc += (float)(r7 & 0x7FFFu) * W_INV * __uint_as_float((uint)b7 << 16);
    }
    for (; k + 4 <= e; k += 4) {
        uint r0 = rec[k], r1 = rec[k+1], r2 = rec[k+2], r3 = rec[k+3];
        ushort b0 = emb16[(size_t)(r0 >> 15) * DIM + lane];
        ushort b1 = emb16[(size_t)(r1 >> 15) * DIM + lane];
        ushort b2 = emb16[(size_t)(r2 >> 15) * DIM + lane];
        ushort b3 = emb16[(size_t)(r3 >> 15) * DIM + lane];
        acc += (float)(r0 & 0x7FFFu) * W_INV * __uint_as_float((uint)b0 << 16);
        acc += (float)(r1 & 0x7FFFu) * W_INV * __uint_as_float((uint)b1 << 16);
        acc += (float)(r2 & 0x7FFFu) * W_INV * __uint_as_float((uint)b2 << 16);
        acc += (float)(r3 & 0x7FFFu) * W_INV * __uint_as_float((uint)b3 << 16);
    }
    for (; k < e; ++k) {
        uint r0 = rec[k];
        ushort b0 = emb16[(size_t)(r0 >> 15) * DIM + lane];
        acc += (float)(r0 & 0x7FFFu) * W_INV * __uint_as_float((uint)b0 << 16);
    }
    out[(size_t)row * DIM + lane] = acc;
}

// ======================= exact-CSR fallback tier (round-9) ==================
__global__ __launch_bounds__(256) void rank_both_exact(
    const int4* __restrict__ u4, const int4* __restrict__ i4,
    int* __restrict__ cnt, int n_i, int su_shift, int si_shift,
    int4* __restrict__ rank_i, int4* __restrict__ rank_u)
{
    int t = blockIdx.x * blockDim.x + threadIdx.x;
    if (t >= NUM_EDGES / 4) return;
    int4 u = u4[t];
    int4 i = i4[t];
    int4 ri, ru;
    ri.x = atomicAdd(&cnt[(u.x >> su_shift) * NUM_ITEMS + i.x], 1);
    ri.y = atomicAdd(&cnt[(u.y >> su_shift) * NUM_ITEMS + i.y], 1);
    ri.z = atomicAdd(&cnt[(u.z >> su_shift) * NUM_ITEMS + i.z], 1);
    ri.w = atomicAdd(&cnt[(u.w >> su_shift) * NUM_ITEMS + i.w], 1);
    ru.x = atomicAdd(&cnt[n_i + (i.x >> si_shift) * NUM_USERS + u.x], 1);
    ru.y = atomicAdd(&cnt[n_i + (i.y >> si_shift) * NUM_USERS + u.y], 1);
    ru.z = atomicAdd(&cnt[n_i + (i.z >> si_shift) * NUM_USERS + u.z], 1);
    ru.w = atomicAdd(&cnt[n_i + (i.w >> si_shift) * NUM_USERS + u.w], 1);
    rank_i[t] = ri;
    rank_u[t] = ru;
}

__global__ __launch_bounds__(SCAN_THREADS) void scan_block_sums(
    const int* __restrict__ cnt, int* __restrict__ bsum, int n, int chunk)
{
    int b = blockIdx.x, t = threadIdx.x;
    int base = b * chunk;
    int end  = base + chunk < n ? base + chunk : n;
    int tch  = (chunk + SCAN_THREADS - 1) / SCAN_THREADS;
    int s = base + t * tch;
    int e = s + tch < end ? s + tch : end;
    int local = 0;
    for (int i = s; i < e; ++i) local += cnt[i];
    __shared__ int sm[SCAN_THREADS];
    sm[t] = local;
    __syncthreads();
    for (int o = SCAN_THREADS / 2; o > 0; o >>= 1) {
        if (t < o) sm[t] += sm[t + o];
        __syncthreads();
    }
    if (t == 0) bsum[b] = sm[0];
}

__global__ __launch_bounds__(SCAN_NB) void scan_block_offsets(
    const int* __restrict__ bsum, int* __restrict__ boff,
    int* __restrict__ off_end)
{
    int t = threadIdx.x;
    __shared__ int sm[SCAN_NB];
    int v = bsum[t];
    sm[t] = v;
    __syncthreads();
    for (int o = 1; o < SCAN_NB; o <<= 1) {
        int x = (t >= o) ? sm[t - o] : 0;
        __syncthreads();
        sm[t] += x;
        __syncthreads();
    }
    boff[t] = sm[t] - v;
    if (t == SCAN_NB - 1) *off_end = sm[SCAN_NB - 1];
}

__global__ __launch_bounds__(SCAN_THREADS) void scan_local(
    int* __restrict__ cnt, const int* __restrict__ boff, int n, int chunk)
{
    int b = blockIdx.x, t = threadIdx.x;
    int base = b * chunk;
    int end  = base + chunk < n ? base + chunk : n;
    int tch  = (chunk + SCAN_THREADS - 1) / SCAN_THREADS;
    int s = base + t * tch;
    int e = s + tch < end ? s + tch : end;
    int local = 0;
    for (int i = s; i < e; ++i) local += cnt[i];
    __shared__ int sm[SCAN_THREADS];
    sm[t] = local;
    __syncthreads();
    for (int o = 1; o < SCAN_THREADS; o <<= 1) {
        int x = (t >= o) ? sm[t - o] : 0;
        __syncthreads();
        sm[t] += x;
        __syncthreads();
    }
    int run = boff[b] + ((t == 0) ? 0 : sm[t - 1]);
    for (int i = s; i < e; ++i) {
        int c = cnt[i];
        cnt[i] = run;
        run += c;
    }
}

__global__ __launch_bounds__(256) void scatter_all(
    const int4* __restrict__ u4, const int4* __restrict__ i4,
    const float4* __restrict__ n4,
    const int4* __restrict__ rank_i, const int4* __restrict__ rank_u,
    const int* __restrict__ off, int n_i, int su_shift, int si_shift,
    uint* __restrict__ rec)
{
    int t = blockIdx.x * blockDim.x + threadIdx.x;
    if (t >= NUM_EDGES / 4) return;
    int4   u  = u4[t];
    int4   i  = i4[t];
    float4 n  = n4[t];
    int4   ri = rank_i[t];
    int4   ru = rank_u[t];
    uint w0 = (uint)(n.x * W_SCALE + 0.5f); if (w0 > 32767u) w0 = 32767u;
    uint w1 = (uint)(n.y * W_SCALE + 0.5f); if (w1 > 32767u) w1 = 32767u;
    uint w2 = (uint)(n.z * W_SCALE + 0.5f); if (w2 > 32767u) w2 = 32767u;
    uint w3 = (uint)(n.w * W_SCALE + 0.5f); if (w3 > 32767u) w3 = 32767u;
    int pi0 = off[(u.x >> su_shift) * NUM_ITEMS + i.x] + ri.x;
    int pi1 = off[(u.y >> su_shift) * NUM_ITEMS + i.y] + ri.y;
    int pi2 = off[(u.z >> su_shift) * NUM_ITEMS + i.z] + ri.z;
    int pi3 = off[(u.w >> su_shift) * NUM_ITEMS + i.w] + ri.w;
    int pu0 = off[n_i + (i.x >> si_shift) * NUM_USERS + u.x] + ru.x;
    int pu1 = off[n_i + (i.y >> si_shift) * NUM_USERS + u.y] + ru.y;
    int pu2 = off[n_i + (i.z >> si_shift) * NUM_USERS + u.z] + ru.z;
    int pu3 = off[n_i + (i.w >> si_shift) * NUM_USERS + u.w] + ru.w;
    rec[pi0] = ((uint)u.x << 15) | w0;
    rec[pi1] = ((uint)u.y << 15) | w1;
    rec[pi2] = ((uint)u.z << 15) | w2;
    rec[pi3] = ((uint)u.w << 15) | w3;
    rec[pu0] = ((uint)i.x << 15) | w0;
    rec[pu1] = ((uint)i.y << 15) | w1;
    rec[pu2] = ((uint)i.z << 15) | w2;
    rec[pu3] = ((uint)i.w << 15) | w3;
}

__global__ __launch_bounds__(256) void gather_pass(
    const int* __restrict__ off, int bin_base,
    const uint* __restrict__ rec,
    const ushort* __restrict__ emb16,
    float* __restrict__ out, int nrows, int accumulate)
{
    int gid  = blockIdx.x * blockDim.x + threadIdx.x;
    int row  = gid >> 6;
    int lane = gid & 63;
    if (row >= nrows) return;
    int b = bin_base + row;
    int s = off[b];
    int e = off[b + 1];
    float acc = accumulate ? out[(size_t)row * DIM + lane] : 0.f;
    int k = s;
    for (; k + 8 <= e; k += 8) {
        uint r0 = rec[k],   r1 = rec[k+1], r2 = rec[k+2], r3 = rec[k+3];
        uint r4 = rec[k+4], r5 = rec[k+5], r6 = rec[k+6], r7 = rec[k+7];
        ushort b0 = emb16[(size_t)(r0 >> 15) * DIM + lane];
        ushort b1 = emb16[(size_t)(r1 >> 15) * DIM + lane];
        ushort b2 = emb16[(size_t)(r2 >> 15) * DIM + lane];
        ushort b3 = emb16[(size_t)(r3 >> 15) * DIM + lane];
        ushort b4 = emb16[(size_t)(r4 >> 15) * DIM + lane];
        ushort b5 = emb16[(size_t)(r5 >> 15) * DIM + lane];
        ushort b6 = emb16[(size_t)(r6 >> 15) * DIM + lane];
        ushort b7 = emb16[(size_t)(r7 >> 15) * DIM + lane];
        acc += (float)(r0 & 0x7FFFu) * W_INV * __uint_as_float((uint)b0 << 16);
        acc += (float)(r1 & 0x7FFFu) * W_INV * __uint_as_float((uint)b1 << 16);
        acc += (float)(r2 & 0x7FFFu) * W_INV * __uint_as_float((uint)b2 << 16);
        acc += (float)(r3 & 0x7FFFu) * W_INV * __uint_as_float((uint)b3 << 16);
        acc += (float)(r4 & 0x7FFFu) * W_INV * __uint_as_float((uint)b4 << 16);
        acc += (float)(r5 & 0x7FFFu) * W_INV * __uint_as_float((uint)b5 << 16);
        acc += (float)(r6 & 0x7FFFu) * W_INV * __uint_as_float((uint)b6 << 16);
        acc += (float)(r7 & 0x7FFFu) * W_INV * __uint_as_float((uint)b7 << 16);
    }
    for (; k + 4 <= e; k += 4) {
        uint r0 = rec[k], r1 = rec[k+1], r2 = rec[k+2], r3 = rec[k+3];
        ushort b0 = emb16[(size_t)(r0 >> 15) * DIM + lane];
        ushort b1 = emb16[(size_t)(r1 >> 15) * DIM + lane];
        ushort b2 = emb16[(size_t)(r2 >> 15) * DIM + lane];
        ushort b3 = emb16[(size_t)(r3 >> 15) * DIM + lane];
        acc += (float)(r0 & 0x7FFFu) * W_INV * __uint_as_float((uint)b0 << 16);
        acc += (float)(r1 & 0x7FFFu) * W_INV * __uint_as_float((uint)b1 << 16);
        acc += (float)(r2 & 0x7FFFu) * W_INV * __uint_as_float((uint)b2 << 16);
        acc += (float)(r3 & 0x7FFFu) * W_INV * __uint_as_float((uint)b3 << 16);
    }
    for (; k < e; ++k) {
        uint r0 = rec[k];
        ushort b0 = emb16[(size_t)(r0 >> 15) * DIM + lane];
        acc += (float)(r0 & 0x7FFFu) * W_INV * __uint_as_float((uint)b0 << 16);
    }
    out[(size_t)row * DIM + lane] = acc;
}

extern "C" void kernel_launch(void* const* d_in, const int* in_sizes, int n_in,
                              void* d_out, int out_size, void* d_ws, size_t ws_size,
                              hipStream_t stream) {
    const float* user_emb  = (const float*)d_in[0];
    const float* item_emb  = (const float*)d_in[1];
    const float* edge_norm = (const float*)d_in[2];
    const int*   u_idx     = (const int*)d_in[3];
    const int*   i_idx     = (const int*)d_in[4];

    float* agg_users = (float*)d_out;                        // 100000*64
    float* agg_items = agg_users + (size_t)NUM_USERS * DIM;  // 50000*64

    const int un4 = NUM_USERS * DIM / 4;
    const int in4 = NUM_ITEMS * DIM / 4;
    const int eb4 = (NUM_EDGES / 4 + 255) / 256;
    const size_t bf16_bytes = ((size_t)NUM_USERS + NUM_ITEMS) * DIM * sizeof(ushort);

    // ---------- tier 1: padded bins, FUSED rank+scatter ----------
    {
        const int n_i = SLICES_U * NUM_ITEMS;       // 350000
        const int n_u = SLICES_I * NUM_USERS;       // 400000
        const int n_total = n_i + n_u;              // 750000
        const size_t cnt_bytes = (size_t)n_total * sizeof(int);
        const size_t rec_bytes = (size_t)n_total * PAD_CAP * sizeof(uint);
        const size_t need = cnt_bytes + 64 + rec_bytes + 64 + bf16_bytes + 256;
        if (ws_size >= need) {
            char* p = (char*)d_ws;
            int*     cnt    = (int*)p;     p += cnt_bytes;
            p = (char*)(((uintptr_t)p + 63) & ~(uintptr_t)63);
            uint*    rec    = (uint*)p;    p += rec_bytes;
            p = (char*)(((uintptr_t)p + 63) & ~(uintptr_t)63);
            ushort*  ue16   = (ushort*)p;  p += (size_t)NUM_USERS * DIM * sizeof(ushort);
            ushort*  ie16   = (ushort*)p;

            hipMemsetAsync(cnt, 0, cnt_bytes, stream);
            convert_both<<<(un4 + in4 + 255) / 256, 256, 0, stream>>>(
                (const float4*)user_emb, (const float4*)item_emb,
                (ushort4*)ue16, (ushort4*)ie16, un4, in4);
            rank_scatter_pad<<<eb4, 256, 0, stream>>>(
                (const int4*)u_idx, (const int4*)i_idx, (const float4*)edge_norm,
                cnt, n_i, SLICE_SHIFT, SLICE_SHIFT, rec);
            for (int s = 0; s < SLICES_U; ++s) {
                gather_pad<<<((NUM_ITEMS * 64) + 255) / 256, 256, 0, stream>>>(
                    cnt, s * NUM_ITEMS, rec, ue16, agg_items, NUM_ITEMS,
                    s > 0 ? 1 : 0);
            }
            for (int s = 0; s < SLICES_I; ++s) {
                gather_pad<<<((NUM_USERS * 64) + 255) / 256, 256, 0, stream>>>(
                    cnt, n_i + s * NUM_USERS, rec, ie16, agg_users, NUM_USERS,
                    s > 0 ? 1 : 0);
            }
            return;
        }
    }

    // ---------- tier 2/3: exact CSR (round-9 path), sliced or unsliced ------
    {
        const size_t rec_bytes  = (size_t)2 * NUM_EDGES * sizeof(uint);
        const size_t rank_bytes = (size_t)2 * NUM_EDGES * sizeof(int);
        auto need_for = [&](int SU, int SI) -> size_t {
            size_t n_total = (size_t)SU * NUM_ITEMS + (size_t)SI * NUM_USERS;
            size_t off_bytes = (n_total + 1 + 2 * SCAN_NB) * sizeof(int);
            return off_bytes + 64 + rec_bytes + 64 + rank_bytes + 64 + bf16_bytes
                 + 256;
        };
        int SU = 0, SI = 0, su_shift = 17, si_shift = 17;
        if (ws_size >= need_for(SLICES_U, SLICES_I)) {
            SU = SLICES_U; SI = SLICES_I;
            su_shift = SLICE_SHIFT; si_shift = SLICE_SHIFT;
        } else if (ws_size >= need_for(1, 1)) {
            SU = 1; SI = 1;
        }
        if (SU > 0) {
            const int n_i = SU * NUM_ITEMS;
            const int n_u = SI * NUM_USERS;
            const int n_total = n_i + n_u;

            char* p = (char*)d_ws;
            int*   cnt  = (int*)p;   p += (size_t)(n_total + 1) * sizeof(int);
            int*   bsum = (int*)p;   p += (size_t)SCAN_NB * sizeof(int);
            int*   boff = (int*)p;   p += (size_t)SCAN_NB * sizeof(int);
            p = (char*)(((uintptr_t)p + 63) & ~(uintptr_t)63);
            uint*  rec  = (uint*)p;  p += rec_bytes;
            p = (char*)(((uintptr_t)p + 63) & ~(uintptr_t)63);
            int*   rank_i = (int*)p; p += (size_t)NUM_EDGES * sizeof(int);
            int*   rank_u = (int*)p; p += (size_t)NUM_EDGES * sizeof(int);
            p = (char*)(((uintptr_t)p + 63) & ~(uintptr_t)63);
            ushort* ue16 = (ushort*)p; p += (size_t)NUM_USERS * DIM * sizeof(ushort);
            ushort* ie16 = (ushort*)p;

            hipMemsetAsync(cnt, 0, (size_t)(n_total + 1) * sizeof(int), stream);
            convert_both<<<(un4 + in4 + 255) / 256, 256, 0, stream>>>(
                (const float4*)user_emb, (const float4*)item_emb,
                (ushort4*)ue16, (ushort4*)ie16, un4, in4);
            rank_both_exact<<<eb4, 256, 0, stream>>>(
                (const int4*)u_idx, (const int4*)i_idx, cnt, n_i,
                su_shift, si_shift, (int4*)rank_i, (int4*)rank_u);
            const int chunk = (n_total + SCAN_NB - 1) / SCAN_NB;
            scan_block_sums<<<SCAN_NB, SCAN_THREADS, 0, stream>>>(
                cnt, bsum, n_total, chunk);
            scan_block_offsets<<<1, SCAN_NB, 0, stream>>>(bsum, boff, cnt + n_total);
            scan_local<<<SCAN_NB, SCAN_THREADS, 0, stream>>>(
                cnt, boff, n_total, chunk);
            scatter_all<<<eb4, 256, 0, stream>>>(
                (const int4*)u_idx, (const int4*)i_idx, (const float4*)edge_norm,
                (const int4*)rank_i, (const int4*)rank_u,
                cnt, n_i, su_shift, si_shift, rec);
            for (int s = 0; s < SU; ++s) {
                gather_pass<<<((NUM_ITEMS * 64) + 255) / 256, 256, 0, stream>>>(
                    cnt, s * NUM_ITEMS, rec, ue16, agg_items, NUM_ITEMS,
                    s > 0 ? 1 : 0);
            }
            for (int s = 0; s < SI; ++s) {
                gather_pass<<<((NUM_USERS * 64) + 255) / 256, 256, 0, stream>>>(
                    cnt, n_i + s * NUM_USERS, rec, ie16, agg_users, NUM_USERS,
                    s > 0 ? 1 : 0);
            }
            return;
        }
    }

    // ---------- tier 4: scatter-atomic ----------
    hipMemsetAsync(d_out, 0, (size_t)out_size * sizeof(float), stream);
    const long long total_threads = (long long)NUM_EDGES * 64;
    const int blocks = (int)((total_threads + 255) / 256);
    lightgcn_scatter<<<blocks, 256, 0, stream>>>(
        user_emb, item_emb, edge_norm, u_idx, i_idx, agg_users, agg_items);
}

// Round 2
// 780.843 us; speedup vs baseline: 1.3472x; 1.3472x over previous
//
#include <hip/hip_runtime.h>

#define NUM_USERS 100000
#define NUM_ITEMS 50000
#define NUM_EDGES 4000000
#define DIM 64

// Source-table slicing: 1<<15 = 32768 rows/slice = 4 MB bf16 per slice
// (fits per-XCD L2). Round-2 finding: slices 4+2 instead of 7+4 halves the
// gather out[] accumulation traffic and launch count.
#define SLICE_SHIFT 15
#define SLICES_U ((NUM_USERS + (1 << SLICE_SHIFT) - 1) >> SLICE_SHIFT)  // 4
#define SLICES_I ((NUM_ITEMS + (1 << SLICE_SHIFT) - 1) >> SLICE_SHIFT)  // 2

#define SCAN_NB 512
#define SCAN_THREADS 256

// Padded-bin capacity: lambda = 4M/200K = 20 edges/bin per direction.
// P(Poisson(20) >= 57) ~ 1.4e-10/bin -> ~5e-5 expected overflows over 400K
// bins; gather clamps len<=CAP anyway.
#define PAD_CAP 56

// Packed CSR record: (src_row << 15) | w_quant15 (err <= 1.5e-5 << bf16 noise).
#define W_SCALE 32767.0f
#define W_INV   (1.0f / 32767.0f)

// ---------------- fallback: scatter-atomic (round-1 kernel) ----------------
__global__ __launch_bounds__(256) void lightgcn_scatter(
    const float* __restrict__ user_emb,
    const float* __restrict__ item_emb,
    const float* __restrict__ edge_norm,
    const int* __restrict__ u_idx,
    const int* __restrict__ i_idx,
    float* __restrict__ agg_users,
    float* __restrict__ agg_items)
{
    long long gid = (long long)blockIdx.x * blockDim.x + threadIdx.x;
    int edge = (int)(gid >> 6);
    int lane = (int)(gid & 63);
    if (edge >= NUM_EDGES) return;
    int u = u_idx[edge];
    int i = i_idx[edge];
    float n = edge_norm[edge];
    float uval = user_emb[(size_t)u * DIM + lane];
    float ival = item_emb[(size_t)i * DIM + lane];
    atomicAdd(&agg_items[(size_t)i * DIM + lane], n * uval);
    atomicAdd(&agg_users[(size_t)u * DIM + lane], n * ival);
}

// ---------------- bf16 conversion of BOTH embedding tables -----------------
__global__ __launch_bounds__(256) void convert_both(
    const float4* __restrict__ usrc, const float4* __restrict__ isrc,
    ushort4* __restrict__ udst, ushort4* __restrict__ idst,
    int un4, int in4)
{
    int t = blockIdx.x * blockDim.x + threadIdx.x;
    const float4* s; ushort4* d; int idx;
    if (t < un4) { s = usrc; d = udst; idx = t; }
    else if (t < un4 + in4) { s = isrc; d = idst; idx = t - un4; }
    else return;
    float4 v = s[idx];
    ushort4 o;
    uint b;
    b = __float_as_uint(v.x); o.x = (ushort)((b + 0x7FFFu + ((b >> 16) & 1u)) >> 16);
    b = __float_as_uint(v.y); o.y = (ushort)((b + 0x7FFFu + ((b >> 16) & 1u)) >> 16);
    b = __float_as_uint(v.z); o.z = (ushort)((b + 0x7FFFu + ((b >> 16) & 1u)) >> 16);
    b = __float_as_uint(v.w); o.w = (ushort)((b + 0x7FFFu + ((b >> 16) & 1u)) >> 16);
    d[idx] = o;
}

// ---------------- rank + count, with bf16 convert folded in ----------------
// Blocks [0, rank_blocks): 8M device-scope atomics (the ~26 G-ops/s wall,
// ~314 us, VALU/HBM nearly idle). Blocks [rank_blocks, ...): the bf16 table
// conversion — ~57 MB of streaming work that hides entirely under the atomic
// wall (round-2: saves a launch + ~15 us).
// NOTE (round-1 lesson): do NOT fuse the scattered rec stores in here — the
// atomic pass and the scattered-store pass interfere (~25% mutual slowdown)
// and must stay in separate kernels.
__global__ __launch_bounds__(256) void rank_conv(
    const int4* __restrict__ u4, const int4* __restrict__ i4,
    int* __restrict__ cnt, int n_i, int su_shift, int si_shift,
    ushort4* __restrict__ rank_i, ushort4* __restrict__ rank_u,
    const float4* __restrict__ usrc, const float4* __restrict__ isrc,
    ushort4* __restrict__ udst, ushort4* __restrict__ idst,
    int un4, int in4, int rank_blocks)
{
    if ((int)blockIdx.x >= rank_blocks) {
        int ct = (blockIdx.x - rank_blocks) * blockDim.x + threadIdx.x;
        const float4* s; ushort4* d; int idx;
        if (ct < un4) { s = usrc; d = udst; idx = ct; }
        else if (ct < un4 + in4) { s = isrc; d = idst; idx = ct - un4; }
        else return;
        float4 v = s[idx];
        ushort4 o;
        uint b;
        b = __float_as_uint(v.x); o.x = (ushort)((b + 0x7FFFu + ((b >> 16) & 1u)) >> 16);
        b = __float_as_uint(v.y); o.y = (ushort)((b + 0x7FFFu + ((b >> 16) & 1u)) >> 16);
        b = __float_as_uint(v.z); o.z = (ushort)((b + 0x7FFFu + ((b >> 16) & 1u)) >> 16);
        b = __float_as_uint(v.w); o.w = (ushort)((b + 0x7FFFu + ((b >> 16) & 1u)) >> 16);
        d[idx] = o;
        return;
    }
    int t = blockIdx.x * blockDim.x + threadIdx.x;
    if (t >= NUM_EDGES / 4) return;
    int4 u = u4[t];
    int4 i = i4[t];
    ushort4 ri, ru;
    ri.x = (ushort)atomicAdd(&cnt[(u.x >> su_shift) * NUM_ITEMS + i.x], 1);
    ri.y = (ushort)atomicAdd(&cnt[(u.y >> su_shift) * NUM_ITEMS + i.y], 1);
    ri.z = (ushort)atomicAdd(&cnt[(u.z >> su_shift) * NUM_ITEMS + i.z], 1);
    ri.w = (ushort)atomicAdd(&cnt[(u.w >> su_shift) * NUM_ITEMS + i.w], 1);
    ru.x = (ushort)atomicAdd(&cnt[n_i + (i.x >> si_shift) * NUM_USERS + u.x], 1);
    ru.y = (ushort)atomicAdd(&cnt[n_i + (i.y >> si_shift) * NUM_USERS + u.y], 1);
    ru.z = (ushort)atomicAdd(&cnt[n_i + (i.z >> si_shift) * NUM_USERS + u.z], 1);
    ru.w = (ushort)atomicAdd(&cnt[n_i + (i.w >> si_shift) * NUM_USERS + u.w], 1);
    rank_i[t] = ri;
    rank_u[t] = ru;
}

// ---------------- padded scatter: pos = bin*PAD_CAP + rank ------------------
__global__ __launch_bounds__(256) void scatter_pad(
    const int4* __restrict__ u4, const int4* __restrict__ i4,
    const float4* __restrict__ n4,
    const ushort4* __restrict__ rank_i, const ushort4* __restrict__ rank_u,
    int n_i, int su_shift, int si_shift,
    uint* __restrict__ rec)
{
    int t = blockIdx.x * blockDim.x + threadIdx.x;
    if (t >= NUM_EDGES / 4) return;
    int4    u  = u4[t];
    int4    i  = i4[t];
    float4  n  = n4[t];
    ushort4 ri = rank_i[t];
    ushort4 ru = rank_u[t];
    uint w0 = (uint)(n.x * W_SCALE + 0.5f); if (w0 > 32767u) w0 = 32767u;
    uint w1 = (uint)(n.y * W_SCALE + 0.5f); if (w1 > 32767u) w1 = 32767u;
    uint w2 = (uint)(n.z * W_SCALE + 0.5f); if (w2 > 32767u) w2 = 32767u;
    uint w3 = (uint)(n.w * W_SCALE + 0.5f); if (w3 > 32767u) w3 = 32767u;
    size_t pi0 = (size_t)((u.x >> su_shift) * NUM_ITEMS + i.x) * PAD_CAP + ri.x;
    size_t pi1 = (size_t)((u.y >> su_shift) * NUM_ITEMS + i.y) * PAD_CAP + ri.y;
    size_t pi2 = (size_t)((u.z >> su_shift) * NUM_ITEMS + i.z) * PAD_CAP + ri.z;
    size_t pi3 = (size_t)((u.w >> su_shift) * NUM_ITEMS + i.w) * PAD_CAP + ri.w;
    size_t pu0 = (size_t)(n_i + (i.x >> si_shift) * NUM_USERS + u.x) * PAD_CAP + ru.x;
    size_t pu1 = (size_t)(n_i + (i.y >> si_shift) * NUM_USERS + u.y) * PAD_CAP + ru.y;
    size_t pu2 = (size_t)(n_i + (i.z >> si_shift) * NUM_USERS + u.z) * PAD_CAP + ru.z;
    size_t pu3 = (size_t)(n_i + (i.w >> si_shift) * NUM_USERS + u.w) * PAD_CAP + ru.w;
    if (ri.x < PAD_CAP) rec[pi0] = ((uint)u.x << 15) | w0;
    if (ri.y < PAD_CAP) rec[pi1] = ((uint)u.y << 15) | w1;
    if (ri.z < PAD_CAP) rec[pi2] = ((uint)u.z << 15) | w2;
    if (ri.w < PAD_CAP) rec[pi3] = ((uint)u.w << 15) | w3;
    if (ru.x < PAD_CAP) rec[pu0] = ((uint)i.x << 15) | w0;
    if (ru.y < PAD_CAP) rec[pu1] = ((uint)i.y << 15) | w1;
    if (ru.z < PAD_CAP) rec[pu2] = ((uint)i.z << 15) | w2;
    if (ru.w < PAD_CAP) rec[pu3] = ((uint)i.w << 15) | w3;
}

// ---------------- padded gather: one 64-lane wave per dst row ---------------
__global__ __launch_bounds__(256) void gather_pad(
    const int* __restrict__ cnt, int bin_base,
    const uint* __restrict__ rec,
    const ushort* __restrict__ emb16,
    float* __restrict__ out, int nrows, int accumulate)
{
    int gid  = blockIdx.x * blockDim.x + threadIdx.x;
    int row  = gid >> 6;
    int lane = gid & 63;
    if (row >= nrows) return;
    int b = bin_base + row;
    int len = cnt[b];
    if (len > PAD_CAP) len = PAD_CAP;
    size_t s = (size_t)b * PAD_CAP;
    size_t e = s + len;
    float acc = accumulate ? out[(size_t)row * DIM + lane] : 0.f;
    size_t k = s;
    for (; k + 8 <= e; k += 8) {
        uint r0 = rec[k],   r1 = rec[k+1], r2 = rec[k+2], r3 = rec[k+3];
        uint r4 = rec[k+4], r5 = rec[k+5], r6 = rec[k+6], r7 = rec[k+7];
        ushort b0 = emb16[(size_t)(r0 >> 15) * DIM + lane];
        ushort b1 = emb16[(size_t)(r1 >> 15) * DIM + lane];
        ushort b2 = emb16[(size_t)(r2 >> 15) * DIM + lane];
        ushort b3 = emb16[(size_t)(r3 >> 15) * DIM + lane];
        ushort b4 = emb16[(size_t)(r4 >> 15) * DIM + lane];
        ushort b5 = emb16[(size_t)(r5 >> 15) * DIM + lane];
        ushort b6 = emb16[(size_t)(r6 >> 15) * DIM + lane];
        ushort b7 = emb16[(size_t)(r7 >> 15) * DIM + lane];
        acc += (float)(r0 & 0x7FFFu) * W_INV * __uint_as_float((uint)b0 << 16);
        acc += (float)(r1 & 0x7FFFu) * W_INV * __uint_as_float((uint)b1 << 16);
        acc += (float)(r2 & 0x7FFFu) * W_INV * __uint_as_float((uint)b2 << 16);
        acc += (float)(r3 & 0x7FFFu) * W_INV * __uint_as_float((uint)b3 << 16);
        acc += (float)(r4 & 0x7FFFu) * W_INV * __uint_as_float((uint)b4 << 16);
        acc += (float)(r5 & 0x7FFFu) * W_INV * __uint_as_float((uint)b5 << 16);
        acc += (float)(r6 & 0x7FFFu) * W_INV * __uint_as_float((uint)b6 << 16);
        acc += (float)(r7 & 0x7FFFu) * W_INV * __uint_as_float((uint)b7 << 16);
    }
    for (; k + 4 <= e; k += 4) {
        uint r0 = rec[k], r1 = rec[k+1], r2 = rec[k+2], r3 = rec[k+3];
        ushort b0 = emb16[(size_t)(r0 >> 15) * DIM + lane];
        ushort b1 = emb16[(size_t)(r1 >> 15) * DIM + lane];
        ushort b2 = emb16[(size_t)(r2 >> 15) * DIM + lane];
        ushort b3 = emb16[(size_t)(r3 >> 15) * DIM + lane];
        acc += (float)(r0 & 0x7FFFu) * W_INV * __uint_as_float((uint)b0 << 16);
        acc += (float)(r1 & 0x7FFFu) * W_INV * __uint_as_float((uint)b1 << 16);
        acc += (float)(r2 & 0x7FFFu) * W_INV * __uint_as_float((uint)b2 << 16);
        acc += (float)(r3 & 0x7FFFu) * W_INV * __uint_as_float((uint)b3 << 16);
    }
    for (; k < e; ++k) {
        uint r0 = rec[k];
        ushort b0 = emb16[(size_t)(r0 >> 15) * DIM + lane];
        acc += (float)(r0 & 0x7FFFu) * W_INV * __uint_as_float((uint)b0 << 16);
    }
    out[(size_t)row * DIM + lane] = acc;
}

// ======================= exact-CSR fallback tier (round-9) ==================
__global__ __launch_bounds__(256) void rank_both_exact(
    const int4* __restrict__ u4, const int4* __restrict__ i4,
    int* __restrict__ cnt, int n_i, int su_shift, int si_shift,
    int4* __restrict__ rank_i, int4* __restrict__ rank_u)
{
    int t = blockIdx.x * blockDim.x + threadIdx.x;
    if (t >= NUM_EDGES / 4) return;
    int4 u = u4[t];
    int4 i = i4[t];
    int4 ri, ru;
    ri.x = atomicAdd(&cnt[(u.x >> su_shift) * NUM_ITEMS + i.x], 1);
    ri.y = atomicAdd(&cnt[(u.y >> su_shift) * NUM_ITEMS + i.y], 1);
    ri.z = atomicAdd(&cnt[(u.z >> su_shift) * NUM_ITEMS + i.z], 1);
    ri.w = atomicAdd(&cnt[(u.w >> su_shift) * NUM_ITEMS + i.w], 1);
    ru.x = atomicAdd(&cnt[n_i + (i.x >> si_shift) * NUM_USERS + u.x], 1);
    ru.y = atomicAdd(&cnt[n_i + (i.y >> si_shift) * NUM_USERS + u.y], 1);
    ru.z = atomicAdd(&cnt[n_i + (i.z >> si_shift) * NUM_USERS + u.z], 1);
    ru.w = atomicAdd(&cnt[n_i + (i.w >> si_shift) * NUM_USERS + u.w], 1);
    rank_i[t] = ri;
    rank_u[t] = ru;
}

__global__ __launch_bounds__(SCAN_THREADS) void scan_block_sums(
    const int* __restrict__ cnt, int* __restrict__ bsum, int n, int chunk)
{
    int b = blockIdx.x, t = threadIdx.x;
    int base = b * chunk;
    int end  = base + chunk < n ? base + chunk : n;
    int tch  = (chunk + SCAN_THREADS - 1) / SCAN_THREADS;
    int s = base + t * tch;
    int e = s + tch < end ? s + tch : end;
    int local = 0;
    for (int i = s; i < e; ++i) local += cnt[i];
    __shared__ int sm[SCAN_THREADS];
    sm[t] = local;
    __syncthreads();
    for (int o = SCAN_THREADS / 2; o > 0; o >>= 1) {
        if (t < o) sm[t] += sm[t + o];
        __syncthreads();
    }
    if (t == 0) bsum[b] = sm[0];
}

__global__ __launch_bounds__(SCAN_NB) void scan_block_offsets(
    const int* __restrict__ bsum, int* __restrict__ boff,
    int* __restrict__ off_end)
{
    int t = threadIdx.x;
    __shared__ int sm[SCAN_NB];
    int v = bsum[t];
    sm[t] = v;
    __syncthreads();
    for (int o = 1; o < SCAN_NB; o <<= 1) {
        int x = (t >= o) ? sm[t - o] : 0;
        __syncthreads();
        sm[t] += x;
        __syncthreads();
    }
    boff[t] = sm[t] - v;
    if (t == SCAN_NB - 1) *off_end = sm[SCAN_NB - 1];
}

__global__ __launch_bounds__(SCAN_THREADS) void scan_local(
    int* __restrict__ cnt, const int* __restrict__ boff, int n, int chunk)
{
    int b = blockIdx.x, t = threadIdx.x;
    int base = b * chunk;
    int end  = base + chunk < n ? base + chunk : n;
    int tch  = (chunk + SCAN_THREADS - 1) / SCAN_THREADS;
    int s = base + t * tch;
    int e = s + tch < end ? s + tch : end;
    int local = 0;
    for (int i = s; i < e; ++i) local += cnt[i];
    __shared__ int sm[SCAN_THREADS];
    sm[t] = local;
    __syncthreads();
    for (int o = 1; o < SCAN_THREADS; o <<= 1) {
        int x = (t >= o) ? sm[t - o] : 0;
        __syncthreads();
        sm[t] += x;
        __syncthreads();
    }
    int run = boff[b] + ((t == 0) ? 0 : sm[t - 1]);
    for (int i = s; i < e; ++i) {
        int c = cnt[i];
        cnt[i] = run;
        run += c;
    }
}

__global__ __launch_bounds__(256) void scatter_all(
    const int4* __restrict__ u4, const int4* __restrict__ i4,
    const float4* __restrict__ n4,
    const int4* __restrict__ rank_i, const int4* __restrict__ rank_u,
    const int* __restrict__ off, int n_i, int su_shift, int si_shift,
    uint* __restrict__ rec)
{
    int t = blockIdx.x * blockDim.x + threadIdx.x;
    if (t >= NUM_EDGES / 4) return;
    int4   u  = u4[t];
    int4   i  = i4[t];
    float4 n  = n4[t];
    int4   ri = rank_i[t];
    int4   ru = rank_u[t];
    uint w0 = (uint)(n.x * W_SCALE + 0.5f); if (w0 > 32767u) w0 = 32767u;
    uint w1 = (uint)(n.y * W_SCALE + 0.5f); if (w1 > 32767u) w1 = 32767u;
    uint w2 = (uint)(n.z * W_SCALE + 0.5f); if (w2 > 32767u) w2 = 32767u;
    uint w3 = (uint)(n.w * W_SCALE + 0.5f); if (w3 > 32767u) w3 = 32767u;
    int pi0 = off[(u.x >> su_shift) * NUM_ITEMS + i.x] + ri.x;
    int pi1 = off[(u.y >> su_shift) * NUM_ITEMS + i.y] + ri.y;
    int pi2 = off[(u.z >> su_shift) * NUM_ITEMS + i.z] + ri.z;
    int pi3 = off[(u.w >> su_shift) * NUM_ITEMS + i.w] + ri.w;
    int pu0 = off[n_i + (i.x >> si_shift) * NUM_USERS + u.x] + ru.x;
    int pu1 = off[n_i + (i.y >> si_shift) * NUM_USERS + u.y] + ru.y;
    int pu2 = off[n_i + (i.z >> si_shift) * NUM_USERS + u.z] + ru.z;
    int pu3 = off[n_i + (i.w >> si_shift) * NUM_USERS + u.w] + ru.w;
    rec[pi0] = ((uint)u.x << 15) | w0;
    rec[pi1] = ((uint)u.y << 15) | w1;
    rec[pi2] = ((uint)u.z << 15) | w2;
    rec[pi3] = ((uint)u.w << 15) | w3;
    rec[pu0] = ((uint)i.x << 15) | w0;
    rec[pu1] = ((uint)i.y << 15) | w1;
    rec[pu2] = ((uint)i.z << 15) | w2;
    rec[pu3] = ((uint)i.w << 15) | w3;
}

__global__ __launch_bounds__(256) void gather_pass(
    const int* __restrict__ off, int bin_base,
    const uint* __restrict__ rec,
    const ushort* __restrict__ emb16,
    float* __restrict__ out, int nrows, int accumulate)
{
    int gid  = blockIdx.x * blockDim.x + threadIdx.x;
    int row  = gid >> 6;
    int lane = gid & 63;
    if (row >= nrows) return;
    int b = bin_base + row;
    int s = off[b];
    int e = off[b + 1];
    float acc = accumulate ? out[(size_t)row * DIM + lane] : 0.f;
    int k = s;
    for (; k + 8 <= e; k += 8) {
        uint r0 = rec[k],   r1 = rec[k+1], r2 = rec[k+2], r3 = rec[k+3];
        uint r4 = rec[k+4], r5 = rec[k+5], r6 = rec[k+6], r7 = rec[k+7];
        ushort b0 = emb16[(size_t)(r0 >> 15) * DIM + lane];
        ushort b1 = emb16[(size_t)(r1 >> 15) * DIM + lane];
        ushort b2 = emb16[(size_t)(r2 >> 15) * DIM + lane];
        ushort b3 = emb16[(size_t)(r3 >> 15) * DIM + lane];
        ushort b4 = emb16[(size_t)(r4 >> 15) * DIM + lane];
        ushort b5 = emb16[(size_t)(r5 >> 15) * DIM + lane];
        ushort b6 = emb16[(size_t)(r6 >> 15) * DIM + lane];
        ushort b7 = emb16[(size_t)(r7 >> 15) * DIM + lane];
        acc += (float)(r0 & 0x7FFFu) * W_INV * __uint_as_float((uint)b0 << 16);
        acc += (float)(r1 & 0x7FFFu) * W_INV * __uint_as_float((uint)b1 << 16);
        acc += (float)(r2 & 0x7FFFu) * W_INV * __uint_as_float((uint)b2 << 16);
        acc += (float)(r3 & 0x7FFFu) * W_INV * __uint_as_float((uint)b3 << 16);
        acc += (float)(r4 & 0x7FFFu) * W_INV * __uint_as_float((uint)b4 << 16);
        acc += (float)(r5 & 0x7FFFu) * W_INV * __uint_as_float((uint)b5 << 16);
        acc += (float)(r6 & 0x7FFFu) * W_INV * __uint_as_float((uint)b6 << 16);
        acc += (float)(r7 & 0x7FFFu) * W_INV * __uint_as_float((uint)b7 << 16);
    }
    for (; k + 4 <= e; k += 4) {
        uint r0 = rec[k], r1 = rec[k+1], r2 = rec[k+2], r3 = rec[k+3];
        ushort b0 = emb16[(size_t)(r0 >> 15) * DIM + lane];
        ushort b1 = emb16[(size_t)(r1 >> 15) * DIM + lane];
        ushort b2 = emb16[(size_t)(r2 >> 15) * DIM + lane];
        ushort b3 = emb16[(size_t)(r3 >> 15) * DIM + lane];
        acc += (float)(r0 & 0x7FFFu) * W_INV * __uint_as_float((uint)b0 << 16);
        acc += (float)(r1 & 0x7FFFu) * W_INV * __uint_as_float((uint)b1 << 16);
        acc += (float)(r2 & 0x7FFFu) * W_INV * __uint_as_float((uint)b2 << 16);
        acc += (float)(r3 & 0x7FFFu) * W_INV * __uint_as_float((uint)b3 << 16);
    }
    for (; k < e; ++k) {
        uint r0 = rec[k];
        ushort b0 = emb16[(size_t)(r0 >> 15) * DIM + lane];
        acc += (float)(r0 & 0x7FFFu) * W_INV * __uint_as_float((uint)b0 << 16);
    }
    out[(size_t)row * DIM + lane] = acc;
}

extern "C" void kernel_launch(void* const* d_in, const int* in_sizes, int n_in,
                              void* d_out, int out_size, void* d_ws, size_t ws_size,
                              hipStream_t stream) {
    const float* user_emb  = (const float*)d_in[0];
    const float* item_emb  = (const float*)d_in[1];
    const float* edge_norm = (const float*)d_in[2];
    const int*   u_idx     = (const int*)d_in[3];
    const int*   i_idx     = (const int*)d_in[4];

    float* agg_users = (float*)d_out;                        // 100000*64
    float* agg_items = agg_users + (size_t)NUM_USERS * DIM;  // 50000*64

    const int un4 = NUM_USERS * DIM / 4;
    const int in4 = NUM_ITEMS * DIM / 4;
    const int eb4 = (NUM_EDGES / 4 + 255) / 256;
    const int cb  = (un4 + in4 + 255) / 256;
    const size_t bf16_bytes = ((size_t)NUM_USERS + NUM_ITEMS) * DIM * sizeof(ushort);

    // ---------- tier 1: padded bins, split rank / scatter ----------
    {
        const int n_i = SLICES_U * NUM_ITEMS;       // 200000
        const int n_u = SLICES_I * NUM_USERS;       // 200000
        const int n_total = n_i + n_u;              // 400000
        const size_t cnt_bytes  = (size_t)n_total * sizeof(int);
        const size_t rank_bytes = (size_t)2 * NUM_EDGES * sizeof(ushort);
        const size_t rec_bytes  = (size_t)n_total * PAD_CAP * sizeof(uint);
        const size_t need = cnt_bytes + 64 + rank_bytes + 64 + rec_bytes + 64
                          + bf16_bytes + 256;
        if (ws_size >= need) {
            char* p = (char*)d_ws;
            int*     cnt    = (int*)p;     p += cnt_bytes;
            p = (char*)(((uintptr_t)p + 63) & ~(uintptr_t)63);
            ushort*  rank_i = (ushort*)p;  p += (size_t)NUM_EDGES * sizeof(ushort);
            ushort*  rank_u = (ushort*)p;  p += (size_t)NUM_EDGES * sizeof(ushort);
            p = (char*)(((uintptr_t)p + 63) & ~(uintptr_t)63);
            uint*    rec    = (uint*)p;    p += rec_bytes;
            p = (char*)(((uintptr_t)p + 63) & ~(uintptr_t)63);
            ushort*  ue16   = (ushort*)p;  p += (size_t)NUM_USERS * DIM * sizeof(ushort);
            ushort*  ie16   = (ushort*)p;

            hipMemsetAsync(cnt, 0, cnt_bytes, stream);
            // rank (atomic wall) + bf16 convert folded into one launch; the
            // convert's streaming work hides under the idle BW of the wall.
            rank_conv<<<eb4 + cb, 256, 0, stream>>>(
                (const int4*)u_idx, (const int4*)i_idx, cnt, n_i,
                SLICE_SHIFT, SLICE_SHIFT, (ushort4*)rank_i, (ushort4*)rank_u,
                (const float4*)user_emb, (const float4*)item_emb,
                (ushort4*)ue16, (ushort4*)ie16, un4, in4, eb4);
            scatter_pad<<<eb4, 256, 0, stream>>>(
                (const int4*)u_idx, (const int4*)i_idx, (const float4*)edge_norm,
                (const ushort4*)rank_i, (const ushort4*)rank_u,
                n_i, SLICE_SHIFT, SLICE_SHIFT, rec);
            for (int s = 0; s < SLICES_U; ++s) {
                gather_pad<<<((NUM_ITEMS * 64) + 255) / 256, 256, 0, stream>>>(
                    cnt, s * NUM_ITEMS, rec, ue16, agg_items, NUM_ITEMS,
                    s > 0 ? 1 : 0);
            }
            for (int s = 0; s < SLICES_I; ++s) {
                gather_pad<<<((NUM_USERS * 64) + 255) / 256, 256, 0, stream>>>(
                    cnt, n_i + s * NUM_USERS, rec, ie16, agg_users, NUM_USERS,
                    s > 0 ? 1 : 0);
            }
            return;
        }
    }

    // ---------- tier 2/3: exact CSR (round-9 path), sliced or unsliced ------
    {
        const size_t rec_bytes  = (size_t)2 * NUM_EDGES * sizeof(uint);
        const size_t rank_bytes = (size_t)2 * NUM_EDGES * sizeof(int);
        auto need_for = [&](int SU, int SI) -> size_t {
            size_t n_total = (size_t)SU * NUM_ITEMS + (size_t)SI * NUM_USERS;
            size_t off_bytes = (n_total + 1 + 2 * SCAN_NB) * sizeof(int);
            return off_bytes + 64 + rec_bytes + 64 + rank_bytes + 64 + bf16_bytes
                 + 256;
        };
        int SU = 0, SI = 0, su_shift = 17, si_shift = 17;
        if (ws_size >= need_for(SLICES_U, SLICES_I)) {
            SU = SLICES_U; SI = SLICES_I;
            su_shift = SLICE_SHIFT; si_shift = SLICE_SHIFT;
        } else if (ws_size >= need_for(1, 1)) {
            SU = 1; SI = 1;
        }
        if (SU > 0) {
            const int n_i = SU * NUM_ITEMS;
            const int n_u = SI * NUM_USERS;
            const int n_total = n_i + n_u;

            char* p = (char*)d_ws;
            int*   cnt  = (int*)p;   p += (size_t)(n_total + 1) * sizeof(int);
            int*   bsum = (int*)p;   p += (size_t)SCAN_NB * sizeof(int);
            int*   boff = (int*)p;   p += (size_t)SCAN_NB * sizeof(int);
            p = (char*)(((uintptr_t)p + 63) & ~(uintptr_t)63);
            uint*  rec  = (uint*)p;  p += rec_bytes;
            p = (char*)(((uintptr_t)p + 63) & ~(uintptr_t)63);
            int*   rank_i = (int*)p; p += (size_t)NUM_EDGES * sizeof(int);
            int*   rank_u = (int*)p; p += (size_t)NUM_EDGES * sizeof(int);
            p = (char*)(((uintptr_t)p + 63) & ~(uintptr_t)63);
            ushort* ue16 = (ushort*)p; p += (size_t)NUM_USERS * DIM * sizeof(ushort);
            ushort* ie16 = (ushort*)p;

            hipMemsetAsync(cnt, 0, (size_t)(n_total + 1) * sizeof(int), stream);
            convert_both<<<cb, 256, 0, stream>>>(
                (const float4*)user_emb, (const float4*)item_emb,
                (ushort4*)ue16, (ushort4*)ie16, un4, in4);
            rank_both_exact<<<eb4, 256, 0, stream>>>(
                (const int4*)u_idx, (const int4*)i_idx, cnt, n_i,
                su_shift, si_shift, (int4*)rank_i, (int4*)rank_u);
            const int chunk = (n_total + SCAN_NB - 1) / SCAN_NB;
            scan_block_sums<<<SCAN_NB, SCAN_THREADS, 0, stream>>>(
                cnt, bsum, n_total, chunk);
            scan_block_offsets<<<1, SCAN_NB, 0, stream>>>(bsum, boff, cnt + n_total);
            scan_local<<<SCAN_NB, SCAN_THREADS, 0, stream>>>(
                cnt, boff, n_total, chunk);
            scatter_all<<<eb4, 256, 0, stream>>>(
                (const int4*)u_idx, (const int4*)i_idx, (const float4*)edge_norm,
                (const int4*)rank_i, (const int4*)rank_u,
                cnt, n_i, su_shift, si_shift, rec);
            for (int s = 0; s < SU; ++s) {
                gather_pass<<<((NUM_ITEMS * 64) + 255) / 256, 256, 0, stream>>>(
                    cnt, s * NUM_ITEMS, rec, ue16, agg_items, NUM_ITEMS,
                    s > 0 ? 1 : 0);
            }
            for (int s = 0; s < SI; ++s) {
                gather_pass<<<((NUM_USERS * 64) + 255) / 256, 256, 0, stream>>>(
                    cnt, n_i + s * NUM_USERS, rec, ie16, agg_users, NUM_USERS,
                    s > 0 ? 1 : 0);
            }
            return;
        }
    }

    // ---------- tier 4: scatter-atomic ----------
    hipMemsetAsync(d_out, 0, (size_t)out_size * sizeof(float), stream);
    const long long total_threads = (long long)NUM_EDGES * 64;
    const int blocks = (int)((total_threads + 255) / 256);
    lightgcn_scatter<<<blocks, 256, 0, stream>>>(
        user_emb, item_emb, edge_norm, u_idx, i_idx, agg_users, agg_items);
}

// Round 4
// 527.499 us; speedup vs baseline: 1.9942x; 1.4803x over previous
//
#include <hip/hip_runtime.h>

#define NUM_USERS 100000
#define NUM_ITEMS 50000
#define NUM_EDGES 4000000
#define DIM 64

// Source-table slicing: 1<<15 = 32768 rows/slice = 4 MB bf16 per slice.
#define SLICE_SHIFT 15
#define SLICES_U ((NUM_USERS + (1 << SLICE_SHIFT) - 1) >> SLICE_SHIFT)  // 4
#define SLICES_I ((NUM_ITEMS + (1 << SLICE_SHIFT) - 1) >> SLICE_SHIFT)  // 2

#define N_I (SLICES_U * NUM_ITEMS)   // 200000 item-direction bins
#define N_U (SLICES_I * NUM_USERS)   // 200000 user-direction bins
#define N_TOTAL (N_I + N_U)          // 400000

#define SCAN_NB 512
#define SCAN_THREADS 256

// ---- two-level bucket partition ------------------------------------------
// Round-3 lesson: slice densities are NON-uniform (full slice -> 26.2
// edges/bin -> 13.4K/bucket, exceeding any "average-based" cap). So bucket
// extents are computed EXACTLY via a counting pre-pass + 782-entry scan;
// no capacity guard, no drops, pairBuf exactly 8M entries.
#define PCHUNK 4096                    // edges per partition workgroup
#define BUK_SHIFT 9                    // 512 bins per bucket
#define NBUK_I ((N_I + 511) >> 9)      // 391
#define NBUK_U ((N_U + 511) >> 9)      // 391
#define NBUK (NBUK_I + NBUK_U)         // 782

// Packed CSR record: (src_row << 15) | w_quant15 (err <= 1.5e-5 << bf16 noise).
#define W_SCALE 32767.0f
#define W_INV   (1.0f / 32767.0f)

// ---------------- fallback: scatter-atomic (round-1 kernel) ----------------
__global__ __launch_bounds__(256) void lightgcn_scatter(
    const float* __restrict__ user_emb,
    const float* __restrict__ item_emb,
    const float* __restrict__ edge_norm,
    const int* __restrict__ u_idx,
    const int* __restrict__ i_idx,
    float* __restrict__ agg_users,
    float* __restrict__ agg_items)
{
    long long gid = (long long)blockIdx.x * blockDim.x + threadIdx.x;
    int edge = (int)(gid >> 6);
    int lane = (int)(gid & 63);
    if (edge >= NUM_EDGES) return;
    int u = u_idx[edge];
    int i = i_idx[edge];
    float n = edge_norm[edge];
    float uval = user_emb[(size_t)u * DIM + lane];
    float ival = item_emb[(size_t)i * DIM + lane];
    atomicAdd(&agg_items[(size_t)i * DIM + lane], n * uval);
    atomicAdd(&agg_users[(size_t)u * DIM + lane], n * ival);
}

// ---------------- bf16 conversion of BOTH embedding tables -----------------
__global__ __launch_bounds__(256) void convert_both(
    const float4* __restrict__ usrc, const float4* __restrict__ isrc,
    ushort4* __restrict__ udst, ushort4* __restrict__ idst,
    int un4, int in4)
{
    int t = blockIdx.x * blockDim.x + threadIdx.x;
    const float4* s; ushort4* d; int idx;
    if (t < un4) { s = usrc; d = udst; idx = t; }
    else if (t < un4 + in4) { s = isrc; d = idst; idx = t - un4; }
    else return;
    float4 v = s[idx];
    ushort4 o;
    uint b;
    b = __float_as_uint(v.x); o.x = (ushort)((b + 0x7FFFu + ((b >> 16) & 1u)) >> 16);
    b = __float_as_uint(v.y); o.y = (ushort)((b + 0x7FFFu + ((b >> 16) & 1u)) >> 16);
    b = __float_as_uint(v.z); o.z = (ushort)((b + 0x7FFFu + ((b >> 16) & 1u)) >> 16);
    b = __float_as_uint(v.w); o.w = (ushort)((b + 0x7FFFu + ((b >> 16) & 1u)) >> 16);
    d[idx] = o;
}

// ---------------- phase A: exact per-bucket counts (+ convert folded) -------
__global__ __launch_bounds__(256) void bucket_hist_conv(
    const int* __restrict__ u_idx, const int* __restrict__ i_idx,
    int* __restrict__ bukCnt,
    const float4* __restrict__ usrc, const float4* __restrict__ isrc,
    ushort4* __restrict__ udst, ushort4* __restrict__ idst,
    int un4, int in4, int hist_blocks)
{
    __shared__ uint hist[NBUK];
    if ((int)blockIdx.x >= hist_blocks) {
        int ct = (blockIdx.x - hist_blocks) * blockDim.x + threadIdx.x;
        const float4* s; ushort4* d; int idx;
        if (ct < un4) { s = usrc; d = udst; idx = ct; }
        else if (ct < un4 + in4) { s = isrc; d = idst; idx = ct - un4; }
        else return;
        float4 v = s[idx];
        ushort4 o;
        uint b;
        b = __float_as_uint(v.x); o.x = (ushort)((b + 0x7FFFu + ((b >> 16) & 1u)) >> 16);
        b = __float_as_uint(v.y); o.y = (ushort)((b + 0x7FFFu + ((b >> 16) & 1u)) >> 16);
        b = __float_as_uint(v.z); o.z = (ushort)((b + 0x7FFFu + ((b >> 16) & 1u)) >> 16);
        b = __float_as_uint(v.w); o.w = (ushort)((b + 0x7FFFu + ((b >> 16) & 1u)) >> 16);
        d[idx] = o;
        return;
    }
    int t = threadIdx.x;
    for (int b = t; b < NBUK; b += 256) hist[b] = 0;
    __syncthreads();
    int e0 = blockIdx.x * PCHUNK;
    int ecnt = NUM_EDGES - e0; if (ecnt > PCHUNK) ecnt = PCHUNK;
    for (int k = t; k < ecnt; k += 256) {
        int u = u_idx[e0 + k];
        int i = i_idx[e0 + k];
        atomicAdd(&hist[((u >> SLICE_SHIFT) * NUM_ITEMS + i) >> BUK_SHIFT], 1u);
        atomicAdd(&hist[NBUK_I + (((i >> SLICE_SHIFT) * NUM_USERS + u) >> BUK_SHIFT)], 1u);
    }
    __syncthreads();
    for (int b = t; b < NBUK; b += 256) {
        uint h = hist[b];
        if (h) atomicAdd(&bukCnt[b], (int)h);
    }
}

// ---------------- phase B: scan 782 bucket counts (single WG) ---------------
__global__ __launch_bounds__(256) void bucket_scan(
    const int* __restrict__ bukCnt, int* __restrict__ bukOff,
    int* __restrict__ gBukCur, int* __restrict__ off_last)
{
    __shared__ int sm[256];
    int t = threadIdx.x;
    int b4 = t * 4;
    int v0 = 0, v1 = 0, v2 = 0, v3 = 0;
    if (b4 + 0 < NBUK) v0 = bukCnt[b4 + 0];
    if (b4 + 1 < NBUK) v1 = bukCnt[b4 + 1];
    if (b4 + 2 < NBUK) v2 = bukCnt[b4 + 2];
    if (b4 + 3 < NBUK) v3 = bukCnt[b4 + 3];
    sm[t] = v0 + v1 + v2 + v3;
    __syncthreads();
    for (int o = 1; o < 256; o <<= 1) {
        int x = (t >= o) ? sm[t - o] : 0;
        __syncthreads();
        sm[t] += x;
        __syncthreads();
    }
    int excl = (t == 0) ? 0 : sm[t - 1];
    if (b4 + 0 < NBUK) { bukOff[b4 + 0] = excl;            gBukCur[b4 + 0] = excl; }
    if (b4 + 1 < NBUK) { int e = excl + v0;                bukOff[b4 + 1] = e; gBukCur[b4 + 1] = e; }
    if (b4 + 2 < NBUK) { int e = excl + v0 + v1;           bukOff[b4 + 2] = e; gBukCur[b4 + 2] = e; }
    if (b4 + 3 < NBUK) { int e = excl + v0 + v1 + v2;      bukOff[b4 + 3] = e; gBukCur[b4 + 3] = e; }
    if (t == 255) bukOff[NBUK] = sm[255];
    if (t == 0) *off_last = 2 * NUM_EDGES;   // off[N_TOTAL]
}

// ---------------- phase C: per-WG LDS counting-sort into exact slabs --------
// Replaces BOTH scattered-4B-op passes (rank atomics + rec stores, the
// ~26 G-ops/s wall from rounds 0-2) with bucket-sorted pair writes: a wave's
// 64 consecutive sorted slots span few buckets -> coalesced segments.
__global__ __launch_bounds__(256) void partition_pairs(
    const int* __restrict__ u_idx, const int* __restrict__ i_idx,
    const float* __restrict__ edge_norm,
    int* __restrict__ gBukCur,
    uint* __restrict__ pairRec, ushort* __restrict__ pairBin)
{
    __shared__ uint recS[2 * PCHUNK];   // 32 KB packed records, bucket-sorted
    __shared__ uint bbS[2 * PCHUNK];    // 32 KB (buk<<9)|lbin per slot
    __shared__ uint hist[NBUK];
    __shared__ uint cursor[NBUK];
    __shared__ uint gbase[NBUK];
    __shared__ uint scanTmp[256];

    int t  = threadIdx.x;
    int e0 = blockIdx.x * PCHUNK;
    int ecnt = NUM_EDGES - e0; if (ecnt > PCHUNK) ecnt = PCHUNK;

    for (int b = t; b < NBUK; b += 256) hist[b] = 0;
    __syncthreads();

    // pass 1: bucket histogram (both directions)
    for (int k = t; k < ecnt; k += 256) {
        int u = u_idx[e0 + k];
        int i = i_idx[e0 + k];
        atomicAdd(&hist[((u >> SLICE_SHIFT) * NUM_ITEMS + i) >> BUK_SHIFT], 1u);
        atomicAdd(&hist[NBUK_I + (((i >> SLICE_SHIFT) * NUM_USERS + u) >> BUK_SHIFT)], 1u);
    }
    __syncthreads();

    // exclusive scan hist -> cursor
    int base4 = t * 4;
    uint v0 = 0, v1 = 0, v2 = 0, v3 = 0;
    if (base4 + 0 < NBUK) v0 = hist[base4 + 0];
    if (base4 + 1 < NBUK) v1 = hist[base4 + 1];
    if (base4 + 2 < NBUK) v2 = hist[base4 + 2];
    if (base4 + 3 < NBUK) v3 = hist[base4 + 3];
    scanTmp[t] = v0 + v1 + v2 + v3;
    __syncthreads();
    for (int o = 1; o < 256; o <<= 1) {
        uint x = (t >= o) ? scanTmp[t - o] : 0;
        __syncthreads();
        scanTmp[t] += x;
        __syncthreads();
    }
    uint excl = (t == 0) ? 0u : scanTmp[t - 1];
    if (base4 + 0 < NBUK) cursor[base4 + 0] = excl;
    if (base4 + 1 < NBUK) cursor[base4 + 1] = excl + v0;
    if (base4 + 2 < NBUK) cursor[base4 + 2] = excl + v0 + v1;
    if (base4 + 3 < NBUK) cursor[base4 + 3] = excl + v0 + v1 + v2;
    __syncthreads();

    // pass 2: stage pairs into bucket-sorted LDS order
    for (int k = t; k < ecnt; k += 256) {
        int u = u_idx[e0 + k];
        int i = i_idx[e0 + k];
        float n = edge_norm[e0 + k];
        uint w = (uint)(n * W_SCALE + 0.5f); if (w > 32767u) w = 32767u;
        int binI = (u >> SLICE_SHIFT) * NUM_ITEMS + i;
        int binU = (i >> SLICE_SHIFT) * NUM_USERS + u;
        uint bI = (uint)(binI >> BUK_SHIFT);
        uint bU = (uint)(NBUK_I + (binU >> BUK_SHIFT));
        uint rI = atomicAdd(&cursor[bI], 1u);
        recS[rI] = ((uint)u << 15) | w;
        bbS[rI]  = (bI << BUK_SHIFT) | (uint)(binI & 511);
        uint rU = atomicAdd(&cursor[bU], 1u);
        recS[rU] = ((uint)i << 15) | w;
        bbS[rU]  = (bU << BUK_SHIFT) | (uint)(binU & 511);
    }
    __syncthreads();

    // one global atomic per (WG, nonempty bucket): exact slab base
    for (int b = t; b < NBUK; b += 256) {
        uint h = hist[b];
        gbase[b] = h ? (uint)atomicAdd(&gBukCur[b], (int)h) : 0u;
    }
    __syncthreads();

    // write out sorted slots; consecutive slots -> consecutive global addrs
    int total = 2 * ecnt;
    for (int s = t; s < total; s += 256) {
        uint bb = bbS[s];
        uint b  = bb >> BUK_SHIFT;
        uint wb = cursor[b] - hist[b];           // bucket's local base in LDS
        uint lpos = gbase[b] + ((uint)s - wb);   // exact: always in range
        pairRec[lpos] = recS[s];
        pairBin[lpos] = (ushort)(bb & 511u);
    }
}

// ---------------- phase D: per-bucket CSR offsets + placement (fused) -------
// Bucket extents are exact and bins within a bucket are contiguous, so the
// global 400K-bin scan is replaced by a local 512-entry LDS scan per bucket.
__global__ __launch_bounds__(256) void bucket_fill(
    const int* __restrict__ bukOff,
    const uint* __restrict__ pairRec, const ushort* __restrict__ pairBin,
    int* __restrict__ off, uint* __restrict__ rec)
{
    __shared__ uint lcnt[512];
    __shared__ uint cur[512];
    __shared__ uint scanTmp[256];
    int b = blockIdx.x, t = threadIdx.x;
    lcnt[t] = 0; lcnt[t + 256] = 0;
    __syncthreads();
    int s0 = bukOff[b], s1 = bukOff[b + 1];
    int n = s1 - s0;
    for (int k = t; k < n; k += 256)
        atomicAdd(&lcnt[pairBin[s0 + k]], 1u);
    __syncthreads();
    // exclusive scan of 512 counts (2 per thread)
    uint a0 = lcnt[2 * t], a1 = lcnt[2 * t + 1];
    scanTmp[t] = a0 + a1;
    __syncthreads();
    for (int o = 1; o < 256; o <<= 1) {
        uint x = (t >= o) ? scanTmp[t - o] : 0;
        __syncthreads();
        scanTmp[t] += x;
        __syncthreads();
    }
    uint excl = (t == 0) ? 0u : scanTmp[t - 1];
    cur[2 * t]     = excl;
    cur[2 * t + 1] = excl + a0;
    __syncthreads();
    // write CSR offsets for this bucket's real bins
    int gbin0, dirEnd;
    if (b < NBUK_I) { gbin0 = b << BUK_SHIFT; dirEnd = N_I; }
    else { gbin0 = N_I + ((b - NBUK_I) << BUK_SHIFT); dirEnd = N_TOTAL; }
    int lim = dirEnd - gbin0; if (lim > 512) lim = 512;
    if (2 * t     < lim) off[gbin0 + 2 * t]     = s0 + (int)cur[2 * t];
    if (2 * t + 1 < lim) off[gbin0 + 2 * t + 1] = s0 + (int)cur[2 * t + 1];
    __syncthreads();   // off-writes must read cur before placement mutates it
    // place records (stores confined to this bucket's contiguous span)
    for (int k = t; k < n; k += 256) {
        uint lbin = pairBin[s0 + k];
        uint r = atomicAdd(&cur[lbin], 1u);
        rec[(size_t)s0 + r] = pairRec[s0 + k];
    }
}

// ======================= scan kernels (tier 2/3 only) =======================
__global__ __launch_bounds__(SCAN_THREADS) void scan_block_sums(
    const int* __restrict__ cnt, int* __restrict__ bsum, int n, int chunk)
{
    int b = blockIdx.x, t = threadIdx.x;
    int base = b * chunk;
    int end  = base + chunk < n ? base + chunk : n;
    int tch  = (chunk + SCAN_THREADS - 1) / SCAN_THREADS;
    int s = base + t * tch;
    int e = s + tch < end ? s + tch : end;
    int local = 0;
    for (int i = s; i < e; ++i) local += cnt[i];
    __shared__ int sm[SCAN_THREADS];
    sm[t] = local;
    __syncthreads();
    for (int o = SCAN_THREADS / 2; o > 0; o >>= 1) {
        if (t < o) sm[t] += sm[t + o];
        __syncthreads();
    }
    if (t == 0) bsum[b] = sm[0];
}

__global__ __launch_bounds__(SCAN_NB) void scan_block_offsets(
    const int* __restrict__ bsum, int* __restrict__ boff,
    int* __restrict__ off_end)
{
    int t = threadIdx.x;
    __shared__ int sm[SCAN_NB];
    int v = bsum[t];
    sm[t] = v;
    __syncthreads();
    for (int o = 1; o < SCAN_NB; o <<= 1) {
        int x = (t >= o) ? sm[t - o] : 0;
        __syncthreads();
        sm[t] += x;
        __syncthreads();
    }
    boff[t] = sm[t] - v;
    if (t == SCAN_NB - 1) *off_end = sm[SCAN_NB - 1];
}

__global__ __launch_bounds__(SCAN_THREADS) void scan_local(
    int* __restrict__ cnt, const int* __restrict__ boff, int n, int chunk)
{
    int b = blockIdx.x, t = threadIdx.x;
    int base = b * chunk;
    int end  = base + chunk < n ? base + chunk : n;
    int tch  = (chunk + SCAN_THREADS - 1) / SCAN_THREADS;
    int s = base + t * tch;
    int e = s + tch < end ? s + tch : end;
    int local = 0;
    for (int i = s; i < e; ++i) local += cnt[i];
    __shared__ int sm[SCAN_THREADS];
    sm[t] = local;
    __syncthreads();
    for (int o = 1; o < SCAN_THREADS; o <<= 1) {
        int x = (t >= o) ? sm[t - o] : 0;
        __syncthreads();
        sm[t] += x;
        __syncthreads();
    }
    int run = boff[b] + ((t == 0) ? 0 : sm[t - 1]);
    for (int i = s; i < e; ++i) {
        int c = cnt[i];
        cnt[i] = run;
        run += c;
    }
}

// ======================= exact-CSR fallback tier ============================
__global__ __launch_bounds__(256) void rank_both_exact(
    const int4* __restrict__ u4, const int4* __restrict__ i4,
    int* __restrict__ cnt, int n_i, int su_shift, int si_shift,
    int4* __restrict__ rank_i, int4* __restrict__ rank_u)
{
    int t = blockIdx.x * blockDim.x + threadIdx.x;
    if (t >= NUM_EDGES / 4) return;
    int4 u = u4[t];
    int4 i = i4[t];
    int4 ri, ru;
    ri.x = atomicAdd(&cnt[(u.x >> su_shift) * NUM_ITEMS + i.x], 1);
    ri.y = atomicAdd(&cnt[(u.y >> su_shift) * NUM_ITEMS + i.y], 1);
    ri.z = atomicAdd(&cnt[(u.z >> su_shift) * NUM_ITEMS + i.z], 1);
    ri.w = atomicAdd(&cnt[(u.w >> su_shift) * NUM_ITEMS + i.w], 1);
    ru.x = atomicAdd(&cnt[n_i + (i.x >> si_shift) * NUM_USERS + u.x], 1);
    ru.y = atomicAdd(&cnt[n_i + (i.y >> si_shift) * NUM_USERS + u.y], 1);
    ru.z = atomicAdd(&cnt[n_i + (i.z >> si_shift) * NUM_USERS + u.z], 1);
    ru.w = atomicAdd(&cnt[n_i + (i.w >> si_shift) * NUM_USERS + u.w], 1);
    rank_i[t] = ri;
    rank_u[t] = ru;
}

__global__ __launch_bounds__(256) void scatter_all(
    const int4* __restrict__ u4, const int4* __restrict__ i4,
    const float4* __restrict__ n4,
    const int4* __restrict__ rank_i, const int4* __restrict__ rank_u,
    const int* __restrict__ off, int n_i, int su_shift, int si_shift,
    uint* __restrict__ rec)
{
    int t = blockIdx.x * blockDim.x + threadIdx.x;
    if (t >= NUM_EDGES / 4) return;
    int4   u  = u4[t];
    int4   i  = i4[t];
    float4 n  = n4[t];
    int4   ri = rank_i[t];
    int4   ru = rank_u[t];
    uint w0 = (uint)(n.x * W_SCALE + 0.5f); if (w0 > 32767u) w0 = 32767u;
    uint w1 = (uint)(n.y * W_SCALE + 0.5f); if (w1 > 32767u) w1 = 32767u;
    uint w2 = (uint)(n.z * W_SCALE + 0.5f); if (w2 > 32767u) w2 = 32767u;
    uint w3 = (uint)(n.w * W_SCALE + 0.5f); if (w3 > 32767u) w3 = 32767u;
    int pi0 = off[(u.x >> su_shift) * NUM_ITEMS + i.x] + ri.x;
    int pi1 = off[(u.y >> su_shift) * NUM_ITEMS + i.y] + ri.y;
    int pi2 = off[(u.z >> su_shift) * NUM_ITEMS + i.z] + ri.z;
    int pi3 = off[(u.w >> su_shift) * NUM_ITEMS + i.w] + ri.w;
    int pu0 = off[n_i + (i.x >> si_shift) * NUM_USERS + u.x] + ru.x;
    int pu1 = off[n_i + (i.y >> si_shift) * NUM_USERS + u.y] + ru.y;
    int pu2 = off[n_i + (i.z >> si_shift) * NUM_USERS + u.z] + ru.z;
    int pu3 = off[n_i + (i.w >> si_shift) * NUM_USERS + u.w] + ru.w;
    rec[pi0] = ((uint)u.x << 15) | w0;
    rec[pi1] = ((uint)u.y << 15) | w1;
    rec[pi2] = ((uint)u.z << 15) | w2;
    rec[pi3] = ((uint)u.w << 15) | w3;
    rec[pu0] = ((uint)i.x << 15) | w0;
    rec[pu1] = ((uint)i.y << 15) | w1;
    rec[pu2] = ((uint)i.z << 15) | w2;
    rec[pu3] = ((uint)i.w << 15) | w3;
}

// ---------------- exact-CSR gather: one 64-lane wave per dst row ------------
__global__ __launch_bounds__(256) void gather_pass(
    const int* __restrict__ off, int bin_base,
    const uint* __restrict__ rec,
    const ushort* __restrict__ emb16,
    float* __restrict__ out, int nrows, int accumulate)
{
    int gid  = blockIdx.x * blockDim.x + threadIdx.x;
    int row  = gid >> 6;
    int lane = gid & 63;
    if (row >= nrows) return;
    int b = bin_base + row;
    int s = off[b];
    int e = off[b + 1];
    float acc = accumulate ? out[(size_t)row * DIM + lane] : 0.f;
    int k = s;
    for (; k + 8 <= e; k += 8) {
        uint r0 = rec[k],   r1 = rec[k+1], r2 = rec[k+2], r3 = rec[k+3];
        uint r4 = rec[k+4], r5 = rec[k+5], r6 = rec[k+6], r7 = rec[k+7];
        ushort b0 = emb16[(size_t)(r0 >> 15) * DIM + lane];
        ushort b1 = emb16[(size_t)(r1 >> 15) * DIM + lane];
        ushort b2 = emb16[(size_t)(r2 >> 15) * DIM + lane];
        ushort b3 = emb16[(size_t)(r3 >> 15) * DIM + lane];
        ushort b4 = emb16[(size_t)(r4 >> 15) * DIM + lane];
        ushort b5 = emb16[(size_t)(r5 >> 15) * DIM + lane];
        ushort b6 = emb16[(size_t)(r6 >> 15) * DIM + lane];
        ushort b7 = emb16[(size_t)(r7 >> 15) * DIM + lane];
        acc += (float)(r0 & 0x7FFFu) * W_INV * __uint_as_float((uint)b0 << 16);
        acc += (float)(r1 & 0x7FFFu) * W_INV * __uint_as_float((uint)b1 << 16);
        acc += (float)(r2 & 0x7FFFu) * W_INV * __uint_as_float((uint)b2 << 16);
        acc += (float)(r3 & 0x7FFFu) * W_INV * __uint_as_float((uint)b3 << 16);
        acc += (float)(r4 & 0x7FFFu) * W_INV * __uint_as_float((uint)b4 << 16);
        acc += (float)(r5 & 0x7FFFu) * W_INV * __uint_as_float((uint)b5 << 16);
        acc += (float)(r6 & 0x7FFFu) * W_INV * __uint_as_float((uint)b6 << 16);
        acc += (float)(r7 & 0x7FFFu) * W_INV * __uint_as_float((uint)b7 << 16);
    }
    for (; k + 4 <= e; k += 4) {
        uint r0 = rec[k], r1 = rec[k+1], r2 = rec[k+2], r3 = rec[k+3];
        ushort b0 = emb16[(size_t)(r0 >> 15) * DIM + lane];
        ushort b1 = emb16[(size_t)(r1 >> 15) * DIM + lane];
        ushort b2 = emb16[(size_t)(r2 >> 15) * DIM + lane];
        ushort b3 = emb16[(size_t)(r3 >> 15) * DIM + lane];
        acc += (float)(r0 & 0x7FFFu) * W_INV * __uint_as_float((uint)b0 << 16);
        acc += (float)(r1 & 0x7FFFu) * W_INV * __uint_as_float((uint)b1 << 16);
        acc += (float)(r2 & 0x7FFFu) * W_INV * __uint_as_float((uint)b2 << 16);
        acc += (float)(r3 & 0x7FFFu) * W_INV * __uint_as_float((uint)b3 << 16);
    }
    for (; k < e; ++k) {
        uint r0 = rec[k];
        ushort b0 = emb16[(size_t)(r0 >> 15) * DIM + lane];
        acc += (float)(r0 & 0x7FFFu) * W_INV * __uint_as_float((uint)b0 << 16);
    }
    out[(size_t)row * DIM + lane] = acc;
}

extern "C" void kernel_launch(void* const* d_in, const int* in_sizes, int n_in,
                              void* d_out, int out_size, void* d_ws, size_t ws_size,
                              hipStream_t stream) {
    const float* user_emb  = (const float*)d_in[0];
    const float* item_emb  = (const float*)d_in[1];
    const float* edge_norm = (const float*)d_in[2];
    const int*   u_idx     = (const int*)d_in[3];
    const int*   i_idx     = (const int*)d_in[4];

    float* agg_users = (float*)d_out;                        // 100000*64
    float* agg_items = agg_users + (size_t)NUM_USERS * DIM;  // 50000*64

    const int un4 = NUM_USERS * DIM / 4;
    const int in4 = NUM_ITEMS * DIM / 4;
    const int eb4 = (NUM_EDGES / 4 + 255) / 256;
    const int cb  = (un4 + in4 + 255) / 256;
    const size_t bf16_bytes = ((size_t)NUM_USERS + NUM_ITEMS) * DIM * sizeof(ushort);

    // ---------- tier 1: exact bucket partition -> local-scan CSR ----------
    {
        const size_t off_bytes  = (size_t)(N_TOTAL + 1) * sizeof(int);
        const size_t buk_bytes  = (size_t)(3 * NBUK + 1) * sizeof(int);
        const size_t prec_bytes = (size_t)2 * NUM_EDGES * sizeof(uint);    // 32 MB
        const size_t pbin_bytes = (size_t)2 * NUM_EDGES * sizeof(ushort);  // 16 MB
        const size_t rec_bytes  = (size_t)2 * NUM_EDGES * sizeof(uint);    // 32 MB
        const size_t need = off_bytes + buk_bytes + 64 + prec_bytes + 64
                          + pbin_bytes + 64 + rec_bytes + 64 + bf16_bytes + 256;
        if (ws_size >= need) {
            char* p = (char*)d_ws;
            int*    off     = (int*)p;    p += off_bytes;
            int*    bukCnt  = (int*)p;    p += (size_t)NBUK * sizeof(int);
            int*    bukOff  = (int*)p;    p += (size_t)(NBUK + 1) * sizeof(int);
            int*    gBukCur = (int*)p;    p += (size_t)NBUK * sizeof(int);
            p = (char*)(((uintptr_t)p + 63) & ~(uintptr_t)63);
            uint*   pairRec = (uint*)p;   p += prec_bytes;
            p = (char*)(((uintptr_t)p + 63) & ~(uintptr_t)63);
            ushort* pairBin = (ushort*)p; p += pbin_bytes;
            p = (char*)(((uintptr_t)p + 63) & ~(uintptr_t)63);
            uint*   rec     = (uint*)p;   p += rec_bytes;
            p = (char*)(((uintptr_t)p + 63) & ~(uintptr_t)63);
            ushort* ue16    = (ushort*)p; p += (size_t)NUM_USERS * DIM * sizeof(ushort);
            ushort* ie16    = (ushort*)p;

            const int pwg = (NUM_EDGES + PCHUNK - 1) / PCHUNK;   // 977
            hipMemsetAsync(bukCnt, 0, (size_t)NBUK * sizeof(int), stream);
            bucket_hist_conv<<<pwg + cb, 256, 0, stream>>>(
                u_idx, i_idx, bukCnt,
                (const float4*)user_emb, (const float4*)item_emb,
                (ushort4*)ue16, (ushort4*)ie16, un4, in4, pwg);
            bucket_scan<<<1, 256, 0, stream>>>(bukCnt, bukOff, gBukCur,
                                               off + N_TOTAL);
            partition_pairs<<<pwg, 256, 0, stream>>>(
                u_idx, i_idx, edge_norm, gBukCur, pairRec, pairBin);
            bucket_fill<<<NBUK, 256, 0, stream>>>(
                bukOff, pairRec, pairBin, off, rec);
            for (int s = 0; s < SLICES_U; ++s) {
                gather_pass<<<((NUM_ITEMS * 64) + 255) / 256, 256, 0, stream>>>(
                    off, s * NUM_ITEMS, rec, ue16, agg_items, NUM_ITEMS,
                    s > 0 ? 1 : 0);
            }
            for (int s = 0; s < SLICES_I; ++s) {
                gather_pass<<<((NUM_USERS * 64) + 255) / 256, 256, 0, stream>>>(
                    off, N_I + s * NUM_USERS, rec, ie16, agg_users, NUM_USERS,
                    s > 0 ? 1 : 0);
            }
            return;
        }
    }

    // ---------- tier 2/3: exact CSR via global atomics, sliced or not -------
    {
        const size_t rec_bytes  = (size_t)2 * NUM_EDGES * sizeof(uint);
        const size_t rank_bytes = (size_t)2 * NUM_EDGES * sizeof(int);
        auto need_for = [&](int SU, int SI) -> size_t {
            size_t n_total = (size_t)SU * NUM_ITEMS + (size_t)SI * NUM_USERS;
            size_t off_bytes = (n_total + 1 + 2 * SCAN_NB) * sizeof(int);
            return off_bytes + 64 + rec_bytes + 64 + rank_bytes + 64 + bf16_bytes
                 + 256;
        };
        int SU = 0, SI = 0, su_shift = 17, si_shift = 17;
        if (ws_size >= need_for(SLICES_U, SLICES_I)) {
            SU = SLICES_U; SI = SLICES_I;
            su_shift = SLICE_SHIFT; si_shift = SLICE_SHIFT;
        } else if (ws_size >= need_for(1, 1)) {
            SU = 1; SI = 1;
        }
        if (SU > 0) {
            const int n_i = SU * NUM_ITEMS;
            const int n_u = SI * NUM_USERS;
            const int n_total = n_i + n_u;

            char* p = (char*)d_ws;
            int*   cnt  = (int*)p;   p += (size_t)(n_total + 1) * sizeof(int);
            int*   bsum = (int*)p;   p += (size_t)SCAN_NB * sizeof(int);
            int*   boff = (int*)p;   p += (size_t)SCAN_NB * sizeof(int);
            p = (char*)(((uintptr_t)p + 63) & ~(uintptr_t)63);
            uint*  rec  = (uint*)p;  p += rec_bytes;
            p = (char*)(((uintptr_t)p + 63) & ~(uintptr_t)63);
            int*   rank_i = (int*)p; p += (size_t)NUM_EDGES * sizeof(int);
            int*   rank_u = (int*)p; p += (size_t)NUM_EDGES * sizeof(int);
            p = (char*)(((uintptr_t)p + 63) & ~(uintptr_t)63);
            ushort* ue16 = (ushort*)p; p += (size_t)NUM_USERS * DIM * sizeof(ushort);
            ushort* ie16 = (ushort*)p;

            hipMemsetAsync(cnt, 0, (size_t)(n_total + 1) * sizeof(int), stream);
            convert_both<<<cb, 256, 0, stream>>>(
                (const float4*)user_emb, (const float4*)item_emb,
                (ushort4*)ue16, (ushort4*)ie16, un4, in4);
            rank_both_exact<<<eb4, 256, 0, stream>>>(
                (const int4*)u_idx, (const int4*)i_idx, cnt, n_i,
                su_shift, si_shift, (int4*)rank_i, (int4*)rank_u);
            const int chunk = (n_total + SCAN_NB - 1) / SCAN_NB;
            scan_block_sums<<<SCAN_NB, SCAN_THREADS, 0, stream>>>(
                cnt, bsum, n_total, chunk);
            scan_block_offsets<<<1, SCAN_NB, 0, stream>>>(bsum, boff, cnt + n_total);
            scan_local<<<SCAN_NB, SCAN_THREADS, 0, stream>>>(
                cnt, boff, n_total, chunk);
            scatter_all<<<eb4, 256, 0, stream>>>(
                (const int4*)u_idx, (const int4*)i_idx, (const float4*)edge_norm,
                (const int4*)rank_i, (const int4*)rank_u,
                cnt, n_i, su_shift, si_shift, rec);
            for (int s = 0; s < SU; ++s) {
                gather_pass<<<((NUM_ITEMS * 64) + 255) / 256, 256, 0, stream>>>(
                    cnt, s * NUM_ITEMS, rec, ue16, agg_items, NUM_ITEMS,
                    s > 0 ? 1 : 0);
            }
            for (int s = 0; s < SI; ++s) {
                gather_pass<<<((NUM_USERS * 64) + 255) / 256, 256, 0, stream>>>(
                    cnt, n_i + s * NUM_USERS, rec, ie16, agg_users, NUM_USERS,
                    s > 0 ? 1 : 0);
            }
            return;
        }
    }

    // ---------- tier 4: scatter-atomic ----------
    hipMemsetAsync(d_out, 0, (size_t)out_size * sizeof(float), stream);
    const long long total_threads = (long long)NUM_EDGES * 64;
    const int blocks = (int)((total_threads + 255) / 256);
    lightgcn_scatter<<<blocks, 256, 0, stream>>>(
        user_emb, item_emb, edge_norm, u_idx, i_idx, agg_users, agg_items);
}

// Round 5
// 471.730 us; speedup vs baseline: 2.2300x; 1.1182x over previous
//
#include <hip/hip_runtime.h>

#define NUM_USERS 100000
#define NUM_ITEMS 50000
#define NUM_EDGES 4000000
#define DIM 64

// Source-table slicing: 1<<15 = 32768 rows/slice = 4 MB bf16 per slice
// (slice replicates into each XCD's 4MB L2 during gather).
#define SLICE_SHIFT 15
#define SLICES_U ((NUM_USERS + (1 << SLICE_SHIFT) - 1) >> SLICE_SHIFT)  // 4
#define SLICES_I ((NUM_ITEMS + (1 << SLICE_SHIFT) - 1) >> SLICE_SHIFT)  // 2

#define N_I (SLICES_U * NUM_ITEMS)   // 200000 item-direction bins
#define N_U (SLICES_I * NUM_USERS)   // 200000 user-direction bins
#define N_TOTAL (N_I + N_U)          // 400000

#define SCAN_NB 512
#define SCAN_THREADS 256

// ---- two-level bucket partition --------------------------------------------
// Exact extents (round-3 lesson: densities are non-uniform; never cap by the
// average). Round-5: per-WG histograms are computed ONCE (hist_conv persists
// the 977x782 matrix), a no-atomic matrix scan derives slab bases -> the whole
// CSR build is deterministic with zero global atomics.
#define PCHUNK 4096                    // edges per partition workgroup
#define PWG ((NUM_EDGES + PCHUNK - 1) / PCHUNK)   // 977
#define BUK_SHIFT 9                    // 512 bins per bucket
#define NBUK_I ((N_I + 511) >> 9)      // 391
#define NBUK_U ((N_U + 511) >> 9)      // 391
#define NBUK (NBUK_I + NBUK_U)         // 782

// Max bucket load: full slice -> 26.2 edges/bin * 512 = 13422 expected,
// sigma ~116; STAGE_CAP = 15360 is +16 sigma. Exact fallback path below.
#define STAGE_CAP 15360

// Packed CSR record: (src_row << 15) | w_quant15 (err <= 1.5e-5 << bf16 noise).
#define W_SCALE 32767.0f
#define W_INV   (1.0f / 32767.0f)

// ---------------- fallback: scatter-atomic (round-1 kernel) ----------------
__global__ __launch_bounds__(256) void lightgcn_scatter(
    const float* __restrict__ user_emb,
    const float* __restrict__ item_emb,
    const float* __restrict__ edge_norm,
    const int* __restrict__ u_idx,
    const int* __restrict__ i_idx,
    float* __restrict__ agg_users,
    float* __restrict__ agg_items)
{
    long long gid = (long long)blockIdx.x * blockDim.x + threadIdx.x;
    int edge = (int)(gid >> 6);
    int lane = (int)(gid & 63);
    if (edge >= NUM_EDGES) return;
    int u = u_idx[edge];
    int i = i_idx[edge];
    float n = edge_norm[edge];
    float uval = user_emb[(size_t)u * DIM + lane];
    float ival = item_emb[(size_t)i * DIM + lane];
    atomicAdd(&agg_items[(size_t)i * DIM + lane], n * uval);
    atomicAdd(&agg_users[(size_t)u * DIM + lane], n * ival);
}

// ---------------- bf16 conversion of BOTH embedding tables -----------------
__global__ __launch_bounds__(256) void convert_both(
    const float4* __restrict__ usrc, const float4* __restrict__ isrc,
    ushort4* __restrict__ udst, ushort4* __restrict__ idst,
    int un4, int in4)
{
    int t = blockIdx.x * blockDim.x + threadIdx.x;
    const float4* s; ushort4* d; int idx;
    if (t < un4) { s = usrc; d = udst; idx = t; }
    else if (t < un4 + in4) { s = isrc; d = idst; idx = t - un4; }
    else return;
    float4 v = s[idx];
    ushort4 o;
    uint b;
    b = __float_as_uint(v.x); o.x = (ushort)((b + 0x7FFFu + ((b >> 16) & 1u)) >> 16);
    b = __float_as_uint(v.y); o.y = (ushort)((b + 0x7FFFu + ((b >> 16) & 1u)) >> 16);
    b = __float_as_uint(v.z); o.z = (ushort)((b + 0x7FFFu + ((b >> 16) & 1u)) >> 16);
    b = __float_as_uint(v.w); o.w = (ushort)((b + 0x7FFFu + ((b >> 16) & 1u)) >> 16);
    d[idx] = o;
}

// ---------------- phase A: per-WG bucket histograms (+ convert folded) ------
// Writes the full per-WG histogram row (coalesced, 1.5 MB total) so the
// partition kernel never re-histograms and no global atomics are needed.
__global__ __launch_bounds__(256) void bucket_hist_conv(
    const int* __restrict__ u_idx, const int* __restrict__ i_idx,
    ushort* __restrict__ wgHist,
    const float4* __restrict__ usrc, const float4* __restrict__ isrc,
    ushort4* __restrict__ udst, ushort4* __restrict__ idst,
    int un4, int in4, int hist_blocks)
{
    __shared__ uint hist[NBUK];
    if ((int)blockIdx.x >= hist_blocks) {
        int ct = (blockIdx.x - hist_blocks) * blockDim.x + threadIdx.x;
        const float4* s; ushort4* d; int idx;
        if (ct < un4) { s = usrc; d = udst; idx = ct; }
        else if (ct < un4 + in4) { s = isrc; d = idst; idx = ct - un4; }
        else return;
        float4 v = s[idx];
        ushort4 o;
        uint b;
        b = __float_as_uint(v.x); o.x = (ushort)((b + 0x7FFFu + ((b >> 16) & 1u)) >> 16);
        b = __float_as_uint(v.y); o.y = (ushort)((b + 0x7FFFu + ((b >> 16) & 1u)) >> 16);
        b = __float_as_uint(v.z); o.z = (ushort)((b + 0x7FFFu + ((b >> 16) & 1u)) >> 16);
        b = __float_as_uint(v.w); o.w = (ushort)((b + 0x7FFFu + ((b >> 16) & 1u)) >> 16);
        d[idx] = o;
        return;
    }
    int t = threadIdx.x;
    for (int b = t; b < NBUK; b += 256) hist[b] = 0;
    __syncthreads();
    int e0 = blockIdx.x * PCHUNK;
    int ecnt = NUM_EDGES - e0; if (ecnt > PCHUNK) ecnt = PCHUNK;
    for (int k = t; k < ecnt; k += 256) {
        int u = u_idx[e0 + k];
        int i = i_idx[e0 + k];
        atomicAdd(&hist[((u >> SLICE_SHIFT) * NUM_ITEMS + i) >> BUK_SHIFT], 1u);
        atomicAdd(&hist[NBUK_I + (((i >> SLICE_SHIFT) * NUM_USERS + u) >> BUK_SHIFT)], 1u);
    }
    __syncthreads();
    ushort* row = wgHist + (size_t)blockIdx.x * NBUK;
    for (int b = t; b < NBUK; b += 256) row[b] = (ushort)hist[b];
}

// ---------------- phase B1: per-bucket scan over WGs (no atomics) -----------
// wgPrefixT[b][wg] = sum of wgHist[<wg][b]; bukTot[b] = bucket total.
// Transposed output -> coalesced writes; partition reads one column entry.
__global__ __launch_bounds__(256) void mscan(
    const ushort* __restrict__ wgHist, uint* __restrict__ wgPrefixT,
    int* __restrict__ bukTot)
{
    __shared__ uint sm[256];
    int b = blockIdx.x, t = threadIdx.x;
    int i0 = t * 4;
    uint c0 = 0, c1 = 0, c2 = 0, c3 = 0;
    if (i0 + 0 < PWG) c0 = wgHist[(size_t)(i0 + 0) * NBUK + b];
    if (i0 + 1 < PWG) c1 = wgHist[(size_t)(i0 + 1) * NBUK + b];
    if (i0 + 2 < PWG) c2 = wgHist[(size_t)(i0 + 2) * NBUK + b];
    if (i0 + 3 < PWG) c3 = wgHist[(size_t)(i0 + 3) * NBUK + b];
    sm[t] = c0 + c1 + c2 + c3;
    __syncthreads();
    for (int o = 1; o < 256; o <<= 1) {
        uint x = (t >= o) ? sm[t - o] : 0;
        __syncthreads();
        sm[t] += x;
        __syncthreads();
    }
    uint excl = (t == 0) ? 0u : sm[t - 1];
    uint* orow = wgPrefixT + (size_t)b * PWG;
    if (i0 + 0 < PWG) orow[i0 + 0] = excl;
    if (i0 + 1 < PWG) orow[i0 + 1] = excl + c0;
    if (i0 + 2 < PWG) orow[i0 + 2] = excl + c0 + c1;
    if (i0 + 3 < PWG) orow[i0 + 3] = excl + c0 + c1 + c2;
    if (t == 255) bukTot[b] = (int)sm[255];
}

// ---------------- phase B2: scan 782 bucket totals (single WG) --------------
__global__ __launch_bounds__(256) void bucket_scan(
    const int* __restrict__ bukTot, int* __restrict__ bukOff,
    int* __restrict__ off_last)
{
    __shared__ int sm[256];
    int t = threadIdx.x;
    int b4 = t * 4;
    int v0 = 0, v1 = 0, v2 = 0, v3 = 0;
    if (b4 + 0 < NBUK) v0 = bukTot[b4 + 0];
    if (b4 + 1 < NBUK) v1 = bukTot[b4 + 1];
    if (b4 + 2 < NBUK) v2 = bukTot[b4 + 2];
    if (b4 + 3 < NBUK) v3 = bukTot[b4 + 3];
    sm[t] = v0 + v1 + v2 + v3;
    __syncthreads();
    for (int o = 1; o < 256; o <<= 1) {
        int x = (t >= o) ? sm[t - o] : 0;
        __syncthreads();
        sm[t] += x;
        __syncthreads();
    }
    int excl = (t == 0) ? 0 : sm[t - 1];
    if (b4 + 0 < NBUK) bukOff[b4 + 0] = excl;
    if (b4 + 1 < NBUK) bukOff[b4 + 1] = excl + v0;
    if (b4 + 2 < NBUK) bukOff[b4 + 2] = excl + v0 + v1;
    if (b4 + 3 < NBUK) bukOff[b4 + 3] = excl + v0 + v1 + v2;
    if (t == 255) bukOff[NBUK] = sm[255];
    if (t == 0) *off_last = 2 * NUM_EDGES;   // off[N_TOTAL]
}

// ---------------- phase C: per-WG LDS counting-sort into exact slabs --------
// Loads its precomputed histogram row + slab base; single edge read; no
// global atomics; bucket-sorted coalesced pair writes.
__global__ __launch_bounds__(256) void partition_pairs(
    const int* __restrict__ u_idx, const int* __restrict__ i_idx,
    const float* __restrict__ edge_norm,
    const ushort* __restrict__ wgHist, const uint* __restrict__ wgPrefixT,
    const int* __restrict__ bukOff,
    uint* __restrict__ pairRec, ushort* __restrict__ pairBin)
{
    __shared__ uint recS[2 * PCHUNK];   // 32 KB packed records, bucket-sorted
    __shared__ uint bbS[2 * PCHUNK];    // 32 KB (buk<<9)|lbin per slot
    __shared__ uint hist[NBUK];
    __shared__ uint cursor[NBUK];
    __shared__ uint gbase[NBUK];
    __shared__ uint scanTmp[256];

    int t  = threadIdx.x;
    int wg = blockIdx.x;
    int e0 = wg * PCHUNK;
    int ecnt = NUM_EDGES - e0; if (ecnt > PCHUNK) ecnt = PCHUNK;

    const ushort* hrow = wgHist + (size_t)wg * NBUK;
    for (int b = t; b < NBUK; b += 256) {
        hist[b]  = hrow[b];
        gbase[b] = (uint)bukOff[b] + wgPrefixT[(size_t)b * PWG + wg];
    }
    __syncthreads();

    // exclusive scan hist -> cursor
    int base4 = t * 4;
    uint v0 = 0, v1 = 0, v2 = 0, v3 = 0;
    if (base4 + 0 < NBUK) v0 = hist[base4 + 0];
    if (base4 + 1 < NBUK) v1 = hist[base4 + 1];
    if (base4 + 2 < NBUK) v2 = hist[base4 + 2];
    if (base4 + 3 < NBUK) v3 = hist[base4 + 3];
    scanTmp[t] = v0 + v1 + v2 + v3;
    __syncthreads();
    for (int o = 1; o < 256; o <<= 1) {
        uint x = (t >= o) ? scanTmp[t - o] : 0;
        __syncthreads();
        scanTmp[t] += x;
        __syncthreads();
    }
    uint excl = (t == 0) ? 0u : scanTmp[t - 1];
    if (base4 + 0 < NBUK) cursor[base4 + 0] = excl;
    if (base4 + 1 < NBUK) cursor[base4 + 1] = excl + v0;
    if (base4 + 2 < NBUK) cursor[base4 + 2] = excl + v0 + v1;
    if (base4 + 3 < NBUK) cursor[base4 + 3] = excl + v0 + v1 + v2;
    __syncthreads();

    // stage pairs into bucket-sorted LDS order
    for (int k = t; k < ecnt; k += 256) {
        int u = u_idx[e0 + k];
        int i = i_idx[e0 + k];
        float n = edge_norm[e0 + k];
        uint w = (uint)(n * W_SCALE + 0.5f); if (w > 32767u) w = 32767u;
        int binI = (u >> SLICE_SHIFT) * NUM_ITEMS + i;
        int binU = (i >> SLICE_SHIFT) * NUM_USERS + u;
        uint bI = (uint)(binI >> BUK_SHIFT);
        uint bU = (uint)(NBUK_I + (binU >> BUK_SHIFT));
        uint rI = atomicAdd(&cursor[bI], 1u);
        recS[rI] = ((uint)u << 15) | w;
        bbS[rI]  = (bI << BUK_SHIFT) | (uint)(binI & 511);
        uint rU = atomicAdd(&cursor[bU], 1u);
        recS[rU] = ((uint)i << 15) | w;
        bbS[rU]  = (bU << BUK_SHIFT) | (uint)(binU & 511);
    }
    __syncthreads();

    // write out sorted slots; consecutive slots -> consecutive global addrs
    int total = 2 * ecnt;
    for (int s = t; s < total; s += 256) {
        uint bb = bbS[s];
        uint b  = bb >> BUK_SHIFT;
        uint wb = cursor[b] - hist[b];           // bucket's local base in LDS
        uint lpos = gbase[b] + ((uint)s - wb);   // exact: always in range
        pairRec[lpos] = recS[s];
        pairBin[lpos] = (ushort)(bb & 511u);
    }
}

// ---------------- phase D: per-bucket CSR offsets + LDS-staged placement ----
// Round-5: stage the sorted bucket in LDS, then write the span LINEARLY.
// The round-4 direct version wrote rec in random (atomic-rank) order ->
// 215 MB HBM writeback for 33.6 MB of data (partial-sector drain).
__global__ __launch_bounds__(256) void bucket_fill(
    const int* __restrict__ bukOff,
    const uint* __restrict__ pairRec, const ushort* __restrict__ pairBin,
    int* __restrict__ off, uint* __restrict__ rec)
{
    __shared__ uint recS[STAGE_CAP];   // 60 KB
    __shared__ uint lcnt[512];
    __shared__ uint cur[512];
    __shared__ uint scanTmp[256];
    int b = blockIdx.x, t = threadIdx.x;
    lcnt[t] = 0; lcnt[t + 256] = 0;
    __syncthreads();
    int s0 = bukOff[b], s1 = bukOff[b + 1];
    int n = s1 - s0;
    for (int k = t; k < n; k += 256)
        atomicAdd(&lcnt[pairBin[s0 + k]], 1u);
    __syncthreads();
    // exclusive scan of 512 counts (2 per thread)
    uint a0 = lcnt[2 * t], a1 = lcnt[2 * t + 1];
    scanTmp[t] = a0 + a1;
    __syncthreads();
    for (int o = 1; o < 256; o <<= 1) {
        uint x = (t >= o) ? scanTmp[t - o] : 0;
        __syncthreads();
        scanTmp[t] += x;
        __syncthreads();
    }
    uint excl = (t == 0) ? 0u : scanTmp[t - 1];
    cur[2 * t]     = excl;
    cur[2 * t + 1] = excl + a0;
    __syncthreads();
    // write CSR offsets for this bucket's real bins
    int gbin0, dirEnd;
    if (b < NBUK_I) { gbin0 = b << BUK_SHIFT; dirEnd = N_I; }
    else { gbin0 = N_I + ((b - NBUK_I) << BUK_SHIFT); dirEnd = N_TOTAL; }
    int lim = dirEnd - gbin0; if (lim > 512) lim = 512;
    if (2 * t     < lim) off[gbin0 + 2 * t]     = s0 + (int)cur[2 * t];
    if (2 * t + 1 < lim) off[gbin0 + 2 * t + 1] = s0 + (int)cur[2 * t + 1];
    __syncthreads();   // off-writes must read cur before placement mutates it
    if (n <= STAGE_CAP) {
        for (int k = t; k < n; k += 256) {
            uint lbin = pairBin[s0 + k];
            uint r = atomicAdd(&cur[lbin], 1u);
            recS[r] = pairRec[s0 + k];
        }
        __syncthreads();
        for (int k = t; k < n; k += 256)      // linear, fully-coalesced
            rec[(size_t)s0 + k] = recS[k];
    } else {
        // exact fallback (never expected at this data scale)
        for (int k = t; k < n; k += 256) {
            uint lbin = pairBin[s0 + k];
            uint r = atomicAdd(&cur[lbin], 1u);
            rec[(size_t)s0 + r] = pairRec[s0 + k];
        }
    }
}

// ======================= scan kernels (tier 2/3 only) =======================
__global__ __launch_bounds__(SCAN_THREADS) void scan_block_sums(
    const int* __restrict__ cnt, int* __restrict__ bsum, int n, int chunk)
{
    int b = blockIdx.x, t = threadIdx.x;
    int base = b * chunk;
    int end  = base + chunk < n ? base + chunk : n;
    int tch  = (chunk + SCAN_THREADS - 1) / SCAN_THREADS;
    int s = base + t * tch;
    int e = s + tch < end ? s + tch : end;
    int local = 0;
    for (int i = s; i < e; ++i) local += cnt[i];
    __shared__ int sm[SCAN_THREADS];
    sm[t] = local;
    __syncthreads();
    for (int o = SCAN_THREADS / 2; o > 0; o >>= 1) {
        if (t < o) sm[t] += sm[t + o];
        __syncthreads();
    }
    if (t == 0) bsum[b] = sm[0];
}

__global__ __launch_bounds__(SCAN_NB) void scan_block_offsets(
    const int* __restrict__ bsum, int* __restrict__ boff,
    int* __restrict__ off_end)
{
    int t = threadIdx.x;
    __shared__ int sm[SCAN_NB];
    int v = bsum[t];
    sm[t] = v;
    __syncthreads();
    for (int o = 1; o < SCAN_NB; o <<= 1) {
        int x = (t >= o) ? sm[t - o] : 0;
        __syncthreads();
        sm[t] += x;
        __syncthreads();
    }
    boff[t] = sm[t] - v;
    if (t == SCAN_NB - 1) *off_end = sm[SCAN_NB - 1];
}

__global__ __launch_bounds__(SCAN_THREADS) void scan_local(
    int* __restrict__ cnt, const int* __restrict__ boff, int n, int chunk)
{
    int b = blockIdx.x, t = threadIdx.x;
    int base = b * chunk;
    int end  = base + chunk < n ? base + chunk : n;
    int tch  = (chunk + SCAN_THREADS - 1) / SCAN_THREADS;
    int s = base + t * tch;
    int e = s + tch < end ? s + tch : end;
    int local = 0;
    for (int i = s; i < e; ++i) local += cnt[i];
    __shared__ int sm[SCAN_THREADS];
    sm[t] = local;
    __syncthreads();
    for (int o = 1; o < SCAN_THREADS; o <<= 1) {
        int x = (t >= o) ? sm[t - o] : 0;
        __syncthreads();
        sm[t] += x;
        __syncthreads();
    }
    int run = boff[b] + ((t == 0) ? 0 : sm[t - 1]);
    for (int i = s; i < e; ++i) {
        int c = cnt[i];
        cnt[i] = run;
        run += c;
    }
}

// ======================= exact-CSR fallback tier ============================
__global__ __launch_bounds__(256) void rank_both_exact(
    const int4* __restrict__ u4, const int4* __restrict__ i4,
    int* __restrict__ cnt, int n_i, int su_shift, int si_shift,
    int4* __restrict__ rank_i, int4* __restrict__ rank_u)
{
    int t = blockIdx.x * blockDim.x + threadIdx.x;
    if (t >= NUM_EDGES / 4) return;
    int4 u = u4[t];
    int4 i = i4[t];
    int4 ri, ru;
    ri.x = atomicAdd(&cnt[(u.x >> su_shift) * NUM_ITEMS + i.x], 1);
    ri.y = atomicAdd(&cnt[(u.y >> su_shift) * NUM_ITEMS + i.y], 1);
    ri.z = atomicAdd(&cnt[(u.z >> su_shift) * NUM_ITEMS + i.z], 1);
    ri.w = atomicAdd(&cnt[(u.w >> su_shift) * NUM_ITEMS + i.w], 1);
    ru.x = atomicAdd(&cnt[n_i + (i.x >> si_shift) * NUM_USERS + u.x], 1);
    ru.y = atomicAdd(&cnt[n_i + (i.y >> si_shift) * NUM_USERS + u.y], 1);
    ru.z = atomicAdd(&cnt[n_i + (i.z >> si_shift) * NUM_USERS + u.z], 1);
    ru.w = atomicAdd(&cnt[n_i + (i.w >> si_shift) * NUM_USERS + u.w], 1);
    rank_i[t] = ri;
    rank_u[t] = ru;
}

__global__ __launch_bounds__(256) void scatter_all(
    const int4* __restrict__ u4, const int4* __restrict__ i4,
    const float4* __restrict__ n4,
    const int4* __restrict__ rank_i, const int4* __restrict__ rank_u,
    const int* __restrict__ off, int n_i, int su_shift, int si_shift,
    uint* __restrict__ rec)
{
    int t = blockIdx.x * blockDim.x + threadIdx.x;
    if (t >= NUM_EDGES / 4) return;
    int4   u  = u4[t];
    int4   i  = i4[t];
    float4 n  = n4[t];
    int4   ri = rank_i[t];
    int4   ru = rank_u[t];
    uint w0 = (uint)(n.x * W_SCALE + 0.5f); if (w0 > 32767u) w0 = 32767u;
    uint w1 = (uint)(n.y * W_SCALE + 0.5f); if (w1 > 32767u) w1 = 32767u;
    uint w2 = (uint)(n.z * W_SCALE + 0.5f); if (w2 > 32767u) w2 = 32767u;
    uint w3 = (uint)(n.w * W_SCALE + 0.5f); if (w3 > 32767u) w3 = 32767u;
    int pi0 = off[(u.x >> su_shift) * NUM_ITEMS + i.x] + ri.x;
    int pi1 = off[(u.y >> su_shift) * NUM_ITEMS + i.y] + ri.y;
    int pi2 = off[(u.z >> su_shift) * NUM_ITEMS + i.z] + ri.z;
    int pi3 = off[(u.w >> su_shift) * NUM_ITEMS + i.w] + ri.w;
    int pu0 = off[n_i + (i.x >> si_shift) * NUM_USERS + u.x] + ru.x;
    int pu1 = off[n_i + (i.y >> si_shift) * NUM_USERS + u.y] + ru.y;
    int pu2 = off[n_i + (i.z >> si_shift) * NUM_USERS + u.z] + ru.z;
    int pu3 = off[n_i + (i.w >> si_shift) * NUM_USERS + u.w] + ru.w;
    rec[pi0] = ((uint)u.x << 15) | w0;
    rec[pi1] = ((uint)u.y << 15) | w1;
    rec[pi2] = ((uint)u.z << 15) | w2;
    rec[pi3] = ((uint)u.w << 15) | w3;
    rec[pu0] = ((uint)i.x << 15) | w0;
    rec[pu1] = ((uint)i.y << 15) | w1;
    rec[pu2] = ((uint)i.z << 15) | w2;
    rec[pu3] = ((uint)i.w << 15) | w3;
}

// ---------------- exact-CSR gather: one 64-lane wave per dst row ------------
__global__ __launch_bounds__(256) void gather_pass(
    const int* __restrict__ off, int bin_base,
    const uint* __restrict__ rec,
    const ushort* __restrict__ emb16,
    float* __restrict__ out, int nrows, int accumulate)
{
    int gid  = blockIdx.x * blockDim.x + threadIdx.x;
    int row  = gid >> 6;
    int lane = gid & 63;
    if (row >= nrows) return;
    int b = bin_base + row;
    int s = off[b];
    int e = off[b + 1];
    float acc = accumulate ? out[(size_t)row * DIM + lane] : 0.f;
    int k = s;
    for (; k + 8 <= e; k += 8) {
        uint r0 = rec[k],   r1 = rec[k+1], r2 = rec[k+2], r3 = rec[k+3];
        uint r4 = rec[k+4], r5 = rec[k+5], r6 = rec[k+6], r7 = rec[k+7];
        ushort b0 = emb16[(size_t)(r0 >> 15) * DIM + lane];
        ushort b1 = emb16[(size_t)(r1 >> 15) * DIM + lane];
        ushort b2 = emb16[(size_t)(r2 >> 15) * DIM + lane];
        ushort b3 = emb16[(size_t)(r3 >> 15) * DIM + lane];
        ushort b4 = emb16[(size_t)(r4 >> 15) * DIM + lane];
        ushort b5 = emb16[(size_t)(r5 >> 15) * DIM + lane];
        ushort b6 = emb16[(size_t)(r6 >> 15) * DIM + lane];
        ushort b7 = emb16[(size_t)(r7 >> 15) * DIM + lane];
        acc += (float)(r0 & 0x7FFFu) * W_INV * __uint_as_float((uint)b0 << 16);
        acc += (float)(r1 & 0x7FFFu) * W_INV * __uint_as_float((uint)b1 << 16);
        acc += (float)(r2 & 0x7FFFu) * W_INV * __uint_as_float((uint)b2 << 16);
        acc += (float)(r3 & 0x7FFFu) * W_INV * __uint_as_float((uint)b3 << 16);
        acc += (float)(r4 & 0x7FFFu) * W_INV * __uint_as_float((uint)b4 << 16);
        acc += (float)(r5 & 0x7FFFu) * W_INV * __uint_as_float((uint)b5 << 16);
        acc += (float)(r6 & 0x7FFFu) * W_INV * __uint_as_float((uint)b6 << 16);
        acc += (float)(r7 & 0x7FFFu) * W_INV * __uint_as_float((uint)b7 << 16);
    }
    for (; k + 4 <= e; k += 4) {
        uint r0 = rec[k], r1 = rec[k+1], r2 = rec[k+2], r3 = rec[k+3];
        ushort b0 = emb16[(size_t)(r0 >> 15) * DIM + lane];
        ushort b1 = emb16[(size_t)(r1 >> 15) * DIM + lane];
        ushort b2 = emb16[(size_t)(r2 >> 15) * DIM + lane];
        ushort b3 = emb16[(size_t)(r3 >> 15) * DIM + lane];
        acc += (float)(r0 & 0x7FFFu) * W_INV * __uint_as_float((uint)b0 << 16);
        acc += (float)(r1 & 0x7FFFu) * W_INV * __uint_as_float((uint)b1 << 16);
        acc += (float)(r2 & 0x7FFFu) * W_INV * __uint_as_float((uint)b2 << 16);
        acc += (float)(r3 & 0x7FFFu) * W_INV * __uint_as_float((uint)b3 << 16);
    }
    for (; k < e; ++k) {
        uint r0 = rec[k];
        ushort b0 = emb16[(size_t)(r0 >> 15) * DIM + lane];
        acc += (float)(r0 & 0x7FFFu) * W_INV * __uint_as_float((uint)b0 << 16);
    }
    out[(size_t)row * DIM + lane] = acc;
}

extern "C" void kernel_launch(void* const* d_in, const int* in_sizes, int n_in,
                              void* d_out, int out_size, void* d_ws, size_t ws_size,
                              hipStream_t stream) {
    const float* user_emb  = (const float*)d_in[0];
    const float* item_emb  = (const float*)d_in[1];
    const float* edge_norm = (const float*)d_in[2];
    const int*   u_idx     = (const int*)d_in[3];
    const int*   i_idx     = (const int*)d_in[4];

    float* agg_users = (float*)d_out;                        // 100000*64
    float* agg_items = agg_users + (size_t)NUM_USERS * DIM;  // 50000*64

    const int un4 = NUM_USERS * DIM / 4;
    const int in4 = NUM_ITEMS * DIM / 4;
    const int eb4 = (NUM_EDGES / 4 + 255) / 256;
    const int cb  = (un4 + in4 + 255) / 256;
    const size_t bf16_bytes = ((size_t)NUM_USERS + NUM_ITEMS) * DIM * sizeof(ushort);

    // ---------- tier 1: deterministic bucket partition -> local-scan CSR ----
    {
        const size_t off_bytes  = (size_t)(N_TOTAL + 1) * sizeof(int);
        const size_t buk_bytes  = (size_t)(2 * NBUK + 2) * sizeof(int);
        const size_t wgh_bytes  = (size_t)PWG * NBUK * sizeof(ushort);     // 1.5 MB
        const size_t wgp_bytes  = (size_t)NBUK * PWG * sizeof(uint);       // 3.1 MB
        const size_t prec_bytes = (size_t)2 * NUM_EDGES * sizeof(uint);    // 32 MB
        const size_t pbin_bytes = (size_t)2 * NUM_EDGES * sizeof(ushort);  // 16 MB
        const size_t rec_bytes  = (size_t)2 * NUM_EDGES * sizeof(uint);    // 32 MB
        const size_t need = off_bytes + buk_bytes + 64 + wgh_bytes + 64
                          + wgp_bytes + 64 + prec_bytes + 64 + pbin_bytes + 64
                          + rec_bytes + 64 + bf16_bytes + 256;
        if (ws_size >= need) {
            char* p = (char*)d_ws;
            int*    off     = (int*)p;    p += off_bytes;
            int*    bukTot  = (int*)p;    p += (size_t)NBUK * sizeof(int);
            int*    bukOff  = (int*)p;    p += (size_t)(NBUK + 1) * sizeof(int);
            p = (char*)(((uintptr_t)p + 63) & ~(uintptr_t)63);
            ushort* wgHist  = (ushort*)p; p += wgh_bytes;
            p = (char*)(((uintptr_t)p + 63) & ~(uintptr_t)63);
            uint*   wgPrefixT = (uint*)p; p += wgp_bytes;
            p = (char*)(((uintptr_t)p + 63) & ~(uintptr_t)63);
            uint*   pairRec = (uint*)p;   p += prec_bytes;
            p = (char*)(((uintptr_t)p + 63) & ~(uintptr_t)63);
            ushort* pairBin = (ushort*)p; p += pbin_bytes;
            p = (char*)(((uintptr_t)p + 63) & ~(uintptr_t)63);
            uint*   rec     = (uint*)p;   p += rec_bytes;
            p = (char*)(((uintptr_t)p + 63) & ~(uintptr_t)63);
            ushort* ue16    = (ushort*)p; p += (size_t)NUM_USERS * DIM * sizeof(ushort);
            ushort* ie16    = (ushort*)p;

            bucket_hist_conv<<<PWG + cb, 256, 0, stream>>>(
                u_idx, i_idx, wgHist,
                (const float4*)user_emb, (const float4*)item_emb,
                (ushort4*)ue16, (ushort4*)ie16, un4, in4, PWG);
            mscan<<<NBUK, 256, 0, stream>>>(wgHist, wgPrefixT, bukTot);
            bucket_scan<<<1, 256, 0, stream>>>(bukTot, bukOff, off + N_TOTAL);
            partition_pairs<<<PWG, 256, 0, stream>>>(
                u_idx, i_idx, edge_norm, wgHist, wgPrefixT, bukOff,
                pairRec, pairBin);
            bucket_fill<<<NBUK, 256, 0, stream>>>(
                bukOff, pairRec, pairBin, off, rec);
            for (int s = 0; s < SLICES_U; ++s) {
                gather_pass<<<((NUM_ITEMS * 64) + 255) / 256, 256, 0, stream>>>(
                    off, s * NUM_ITEMS, rec, ue16, agg_items, NUM_ITEMS,
                    s > 0 ? 1 : 0);
            }
            for (int s = 0; s < SLICES_I; ++s) {
                gather_pass<<<((NUM_USERS * 64) + 255) / 256, 256, 0, stream>>>(
                    off, N_I + s * NUM_USERS, rec, ie16, agg_users, NUM_USERS,
                    s > 0 ? 1 : 0);
            }
            return;
        }
    }

    // ---------- tier 2/3: exact CSR via global atomics, sliced or not -------
    {
        const size_t rec_bytes  = (size_t)2 * NUM_EDGES * sizeof(uint);
        const size_t rank_bytes = (size_t)2 * NUM_EDGES * sizeof(int);
        auto need_for = [&](int SU, int SI) -> size_t {
            size_t n_total = (size_t)SU * NUM_ITEMS + (size_t)SI * NUM_USERS;
            size_t off_bytes = (n_total + 1 + 2 * SCAN_NB) * sizeof(int);
            return off_bytes + 64 + rec_bytes + 64 + rank_bytes + 64 + bf16_bytes
                 + 256;
        };
        int SU = 0, SI = 0, su_shift = 17, si_shift = 17;
        if (ws_size >= need_for(SLICES_U, SLICES_I)) {
            SU = SLICES_U; SI = SLICES_I;
            su_shift = SLICE_SHIFT; si_shift = SLICE_SHIFT;
        } else if (ws_size >= need_for(1, 1)) {
            SU = 1; SI = 1;
        }
        if (SU > 0) {
            const int n_i = SU * NUM_ITEMS;
            const int n_u = SI * NUM_USERS;
            const int n_total = n_i + n_u;

            char* p = (char*)d_ws;
            int*   cnt  = (int*)p;   p += (size_t)(n_total + 1) * sizeof(int);
            int*   bsum = (int*)p;   p += (size_t)SCAN_NB * sizeof(int);
            int*   boff = (int*)p;   p += (size_t)SCAN_NB * sizeof(int);
            p = (char*)(((uintptr_t)p + 63) & ~(uintptr_t)63);
            uint*  rec  = (uint*)p;  p += rec_bytes;
            p = (char*)(((uintptr_t)p + 63) & ~(uintptr_t)63);
            int*   rank_i = (int*)p; p += (size_t)NUM_EDGES * sizeof(int);
            int*   rank_u = (int*)p; p += (size_t)NUM_EDGES * sizeof(int);
            p = (char*)(((uintptr_t)p + 63) & ~(uintptr_t)63);
            ushort* ue16 = (ushort*)p; p += (size_t)NUM_USERS * DIM * sizeof(ushort);
            ushort* ie16 = (ushort*)p;

            hipMemsetAsync(cnt, 0, (size_t)(n_total + 1) * sizeof(int), stream);
            convert_both<<<cb, 256, 0, stream>>>(
                (const float4*)user_emb, (const float4*)item_emb,
                (ushort4*)ue16, (ushort4*)ie16, un4, in4);
            rank_both_exact<<<eb4, 256, 0, stream>>>(
                (const int4*)u_idx, (const int4*)i_idx, cnt, n_i,
                su_shift, si_shift, (int4*)rank_i, (int4*)rank_u);
            const int chunk = (n_total + SCAN_NB - 1) / SCAN_NB;
            scan_block_sums<<<SCAN_NB, SCAN_THREADS, 0, stream>>>(
                cnt, bsum, n_total, chunk);
            scan_block_offsets<<<1, SCAN_NB, 0, stream>>>(bsum, boff, cnt + n_total);
            scan_local<<<SCAN_NB, SCAN_THREADS, 0, stream>>>(
                cnt, boff, n_total, chunk);
            scatter_all<<<eb4, 256, 0, stream>>>(
                (const int4*)u_idx, (const int4*)i_idx, (const float4*)edge_norm,
                (const int4*)rank_i, (const int4*)rank_u,
                cnt, n_i, su_shift, si_shift, rec);
            for (int s = 0; s < SU; ++s) {
                gather_pass<<<((NUM_ITEMS * 64) + 255) / 256, 256, 0, stream>>>(
                    cnt, s * NUM_ITEMS, rec, ue16, agg_items, NUM_ITEMS,
                    s > 0 ? 1 : 0);
            }
            for (int s = 0; s < SI; ++s) {
                gather_pass<<<((NUM_USERS * 64) + 255) / 256, 256, 0, stream>>>(
                    cnt, n_i + s * NUM_USERS, rec, ie16, agg_users, NUM_USERS,
                    s > 0 ? 1 : 0);
            }
            return;
        }
    }

    // ---------- tier 4: scatter-atomic ----------
    hipMemsetAsync(d_out, 0, (size_t)out_size * sizeof(float), stream);
    const long long total_threads = (long long)NUM_EDGES * 64;
    const int blocks = (int)((total_threads + 255) / 256);
    lightgcn_scatter<<<blocks, 256, 0, stream>>>(
        user_emb, item_emb, edge_norm, u_idx, i_idx, agg_users, agg_items);
}

// Round 6
// 435.761 us; speedup vs baseline: 2.4140x; 1.0825x over previous
//
#include <hip/hip_runtime.h>

#define NUM_USERS 100000
#define NUM_ITEMS 50000
#define NUM_EDGES 4000000
#define DIM 64

// Source-table slicing: 1<<15 = 32768 rows/slice = 4 MB bf16 per slice.
#define SLICE_SHIFT 15
#define SLICES_U ((NUM_USERS + (1 << SLICE_SHIFT) - 1) >> SLICE_SHIFT)  // 4
#define SLICES_I ((NUM_ITEMS + (1 << SLICE_SHIFT) - 1) >> SLICE_SHIFT)  // 2

#define N_I (SLICES_U * NUM_ITEMS)   // 200000 item-direction bins
#define N_U (SLICES_I * NUM_USERS)   // 200000 user-direction bins
#define N_TOTAL (N_I + N_U)          // 400000

#define SCAN_NB 512
#define SCAN_THREADS 256

// ---- two-level bucket partition --------------------------------------------
// Exact extents (round-3 lesson: densities are non-uniform; never cap by the
// average). Per-WG histograms computed ONCE (hist_conv persists the 977x782
// matrix); no-atomic matrix scan derives slab bases -> deterministic build.
#define PCHUNK 4096                    // edges per partition workgroup
#define PWG ((NUM_EDGES + PCHUNK - 1) / PCHUNK)   // 977
#define BUK_SHIFT 9                    // 512 bins per bucket
#define NBUK_I ((N_I + 511) >> 9)      // 391
#define NBUK_U ((N_U + 511) >> 9)      // 391
#define NBUK (NBUK_I + NBUK_U)         // 782

// Max bucket load: full slice -> 26.2 edges/bin * 512 = 13422 expected,
// sigma ~116; STAGE_CAP = 15360 is +16 sigma. Exact fallback path below.
#define STAGE_CAP 15360
// Round-6: 512 threads (16 waves/CU at 2 WG/CU) — round-5 showed fill was
// latency-bound at 15% occupancy, 8 waves/CU.
#define BF_THREADS 512

// Packed CSR record: (src_row << 15) | w_quant15 (err <= 1.5e-5 << bf16 noise).
#define W_SCALE 32767.0f
#define W_INV   (1.0f / 32767.0f)

// ---------------- fallback: scatter-atomic (round-1 kernel) ----------------
__global__ __launch_bounds__(256) void lightgcn_scatter(
    const float* __restrict__ user_emb,
    const float* __restrict__ item_emb,
    const float* __restrict__ edge_norm,
    const int* __restrict__ u_idx,
    const int* __restrict__ i_idx,
    float* __restrict__ agg_users,
    float* __restrict__ agg_items)
{
    long long gid = (long long)blockIdx.x * blockDim.x + threadIdx.x;
    int edge = (int)(gid >> 6);
    int lane = (int)(gid & 63);
    if (edge >= NUM_EDGES) return;
    int u = u_idx[edge];
    int i = i_idx[edge];
    float n = edge_norm[edge];
    float uval = user_emb[(size_t)u * DIM + lane];
    float ival = item_emb[(size_t)i * DIM + lane];
    atomicAdd(&agg_items[(size_t)i * DIM + lane], n * uval);
    atomicAdd(&agg_users[(size_t)u * DIM + lane], n * ival);
}

// ---------------- bf16 conversion of BOTH embedding tables -----------------
__global__ __launch_bounds__(256) void convert_both(
    const float4* __restrict__ usrc, const float4* __restrict__ isrc,
    ushort4* __restrict__ udst, ushort4* __restrict__ idst,
    int un4, int in4)
{
    int t = blockIdx.x * blockDim.x + threadIdx.x;
    const float4* s; ushort4* d; int idx;
    if (t < un4) { s = usrc; d = udst; idx = t; }
    else if (t < un4 + in4) { s = isrc; d = idst; idx = t - un4; }
    else return;
    float4 v = s[idx];
    ushort4 o;
    uint b;
    b = __float_as_uint(v.x); o.x = (ushort)((b + 0x7FFFu + ((b >> 16) & 1u)) >> 16);
    b = __float_as_uint(v.y); o.y = (ushort)((b + 0x7FFFu + ((b >> 16) & 1u)) >> 16);
    b = __float_as_uint(v.z); o.z = (ushort)((b + 0x7FFFu + ((b >> 16) & 1u)) >> 16);
    b = __float_as_uint(v.w); o.w = (ushort)((b + 0x7FFFu + ((b >> 16) & 1u)) >> 16);
    d[idx] = o;
}

// ---------------- phase A: per-WG bucket histograms (+ convert folded) ------
__global__ __launch_bounds__(256) void bucket_hist_conv(
    const int* __restrict__ u_idx, const int* __restrict__ i_idx,
    ushort* __restrict__ wgHist,
    const float4* __restrict__ usrc, const float4* __restrict__ isrc,
    ushort4* __restrict__ udst, ushort4* __restrict__ idst,
    int un4, int in4, int hist_blocks)
{
    __shared__ uint hist[NBUK];
    if ((int)blockIdx.x >= hist_blocks) {
        int ct = (blockIdx.x - hist_blocks) * blockDim.x + threadIdx.x;
        const float4* s; ushort4* d; int idx;
        if (ct < un4) { s = usrc; d = udst; idx = ct; }
        else if (ct < un4 + in4) { s = isrc; d = idst; idx = ct - un4; }
        else return;
        float4 v = s[idx];
        ushort4 o;
        uint b;
        b = __float_as_uint(v.x); o.x = (ushort)((b + 0x7FFFu + ((b >> 16) & 1u)) >> 16);
        b = __float_as_uint(v.y); o.y = (ushort)((b + 0x7FFFu + ((b >> 16) & 1u)) >> 16);
        b = __float_as_uint(v.z); o.z = (ushort)((b + 0x7FFFu + ((b >> 16) & 1u)) >> 16);
        b = __float_as_uint(v.w); o.w = (ushort)((b + 0x7FFFu + ((b >> 16) & 1u)) >> 16);
        d[idx] = o;
        return;
    }
    int t = threadIdx.x;
    for (int b = t; b < NBUK; b += 256) hist[b] = 0;
    __syncthreads();
    int e0 = blockIdx.x * PCHUNK;
    int ecnt = NUM_EDGES - e0; if (ecnt > PCHUNK) ecnt = PCHUNK;
    for (int k = t; k < ecnt; k += 256) {
        int u = u_idx[e0 + k];
        int i = i_idx[e0 + k];
        atomicAdd(&hist[((u >> SLICE_SHIFT) * NUM_ITEMS + i) >> BUK_SHIFT], 1u);
        atomicAdd(&hist[NBUK_I + (((i >> SLICE_SHIFT) * NUM_USERS + u) >> BUK_SHIFT)], 1u);
    }
    __syncthreads();
    ushort* row = wgHist + (size_t)blockIdx.x * NBUK;
    for (int b = t; b < NBUK; b += 256) row[b] = (ushort)hist[b];
}

// ---------------- phase B1: per-bucket scan over WGs (no atomics) -----------
__global__ __launch_bounds__(256) void mscan(
    const ushort* __restrict__ wgHist, uint* __restrict__ wgPrefixT,
    int* __restrict__ bukTot)
{
    __shared__ uint sm[256];
    int b = blockIdx.x, t = threadIdx.x;
    int i0 = t * 4;
    uint c0 = 0, c1 = 0, c2 = 0, c3 = 0;
    if (i0 + 0 < PWG) c0 = wgHist[(size_t)(i0 + 0) * NBUK + b];
    if (i0 + 1 < PWG) c1 = wgHist[(size_t)(i0 + 1) * NBUK + b];
    if (i0 + 2 < PWG) c2 = wgHist[(size_t)(i0 + 2) * NBUK + b];
    if (i0 + 3 < PWG) c3 = wgHist[(size_t)(i0 + 3) * NBUK + b];
    sm[t] = c0 + c1 + c2 + c3;
    __syncthreads();
    for (int o = 1; o < 256; o <<= 1) {
        uint x = (t >= o) ? sm[t - o] : 0;
        __syncthreads();
        sm[t] += x;
        __syncthreads();
    }
    uint excl = (t == 0) ? 0u : sm[t - 1];
    uint* orow = wgPrefixT + (size_t)b * PWG;
    if (i0 + 0 < PWG) orow[i0 + 0] = excl;
    if (i0 + 1 < PWG) orow[i0 + 1] = excl + c0;
    if (i0 + 2 < PWG) orow[i0 + 2] = excl + c0 + c1;
    if (i0 + 3 < PWG) orow[i0 + 3] = excl + c0 + c1 + c2;
    if (t == 255) bukTot[b] = (int)sm[255];
}

// ---------------- phase B2: scan 782 bucket totals (single WG) --------------
__global__ __launch_bounds__(256) void bucket_scan(
    const int* __restrict__ bukTot, int* __restrict__ bukOff,
    int* __restrict__ off_last)
{
    __shared__ int sm[256];
    int t = threadIdx.x;
    int b4 = t * 4;
    int v0 = 0, v1 = 0, v2 = 0, v3 = 0;
    if (b4 + 0 < NBUK) v0 = bukTot[b4 + 0];
    if (b4 + 1 < NBUK) v1 = bukTot[b4 + 1];
    if (b4 + 2 < NBUK) v2 = bukTot[b4 + 2];
    if (b4 + 3 < NBUK) v3 = bukTot[b4 + 3];
    sm[t] = v0 + v1 + v2 + v3;
    __syncthreads();
    for (int o = 1; o < 256; o <<= 1) {
        int x = (t >= o) ? sm[t - o] : 0;
        __syncthreads();
        sm[t] += x;
        __syncthreads();
    }
    int excl = (t == 0) ? 0 : sm[t - 1];
    if (b4 + 0 < NBUK) bukOff[b4 + 0] = excl;
    if (b4 + 1 < NBUK) bukOff[b4 + 1] = excl + v0;
    if (b4 + 2 < NBUK) bukOff[b4 + 2] = excl + v0 + v1;
    if (b4 + 3 < NBUK) bukOff[b4 + 3] = excl + v0 + v1 + v2;
    if (t == 255) bukOff[NBUK] = sm[255];
    if (t == 0) *off_last = 2 * NUM_EDGES;   // off[N_TOTAL]
}

// ---------------- phase C: per-WG LDS counting-sort into exact slabs --------
__global__ __launch_bounds__(256) void partition_pairs(
    const int* __restrict__ u_idx, const int* __restrict__ i_idx,
    const float* __restrict__ edge_norm,
    const ushort* __restrict__ wgHist, const uint* __restrict__ wgPrefixT,
    const int* __restrict__ bukOff,
    uint* __restrict__ pairRec, ushort* __restrict__ pairBin)
{
    __shared__ uint recS[2 * PCHUNK];   // 32 KB packed records, bucket-sorted
    __shared__ uint bbS[2 * PCHUNK];    // 32 KB (buk<<9)|lbin per slot
    __shared__ uint hist[NBUK];
    __shared__ uint cursor[NBUK];
    __shared__ uint gbase[NBUK];
    __shared__ uint scanTmp[256];

    int t  = threadIdx.x;
    int wg = blockIdx.x;
    int e0 = wg * PCHUNK;
    int ecnt = NUM_EDGES - e0; if (ecnt > PCHUNK) ecnt = PCHUNK;

    const ushort* hrow = wgHist + (size_t)wg * NBUK;
    for (int b = t; b < NBUK; b += 256) {
        hist[b]  = hrow[b];
        gbase[b] = (uint)bukOff[b] + wgPrefixT[(size_t)b * PWG + wg];
    }
    __syncthreads();

    // exclusive scan hist -> cursor
    int base4 = t * 4;
    uint v0 = 0, v1 = 0, v2 = 0, v3 = 0;
    if (base4 + 0 < NBUK) v0 = hist[base4 + 0];
    if (base4 + 1 < NBUK) v1 = hist[base4 + 1];
    if (base4 + 2 < NBUK) v2 = hist[base4 + 2];
    if (base4 + 3 < NBUK) v3 = hist[base4 + 3];
    scanTmp[t] = v0 + v1 + v2 + v3;
    __syncthreads();
    for (int o = 1; o < 256; o <<= 1) {
        uint x = (t >= o) ? scanTmp[t - o] : 0;
        __syncthreads();
        scanTmp[t] += x;
        __syncthreads();
    }
    uint excl = (t == 0) ? 0u : scanTmp[t - 1];
    if (base4 + 0 < NBUK) cursor[base4 + 0] = excl;
    if (base4 + 1 < NBUK) cursor[base4 + 1] = excl + v0;
    if (base4 + 2 < NBUK) cursor[base4 + 2] = excl + v0 + v1;
    if (base4 + 3 < NBUK) cursor[base4 + 3] = excl + v0 + v1 + v2;
    __syncthreads();

    // stage pairs into bucket-sorted LDS order
    for (int k = t; k < ecnt; k += 256) {
        int u = u_idx[e0 + k];
        int i = i_idx[e0 + k];
        float n = edge_norm[e0 + k];
        uint w = (uint)(n * W_SCALE + 0.5f); if (w > 32767u) w = 32767u;
        int binI = (u >> SLICE_SHIFT) * NUM_ITEMS + i;
        int binU = (i >> SLICE_SHIFT) * NUM_USERS + u;
        uint bI = (uint)(binI >> BUK_SHIFT);
        uint bU = (uint)(NBUK_I + (binU >> BUK_SHIFT));
        uint rI = atomicAdd(&cursor[bI], 1u);
        recS[rI] = ((uint)u << 15) | w;
        bbS[rI]  = (bI << BUK_SHIFT) | (uint)(binI & 511);
        uint rU = atomicAdd(&cursor[bU], 1u);
        recS[rU] = ((uint)i << 15) | w;
        bbS[rU]  = (bU << BUK_SHIFT) | (uint)(binU & 511);
    }
    __syncthreads();

    // write out sorted slots; consecutive slots -> consecutive global addrs
    int total = 2 * ecnt;
    for (int s = t; s < total; s += 256) {
        uint bb = bbS[s];
        uint b  = bb >> BUK_SHIFT;
        uint wb = cursor[b] - hist[b];           // bucket's local base in LDS
        uint lpos = gbase[b] + ((uint)s - wb);   // exact: always in range
        pairRec[lpos] = recS[s];
        pairBin[lpos] = (ushort)(bb & 511u);
    }
}

// ---------------- phase D: per-bucket CSR offsets + LDS-staged placement ----
// 512 threads: round-5 showed this kernel latency-bound at 8 waves/CU;
// LDS (66 KB) still allows 2 WG/CU -> 16 waves/CU now.
__global__ __launch_bounds__(BF_THREADS) void bucket_fill(
    const int* __restrict__ bukOff,
    const uint* __restrict__ pairRec, const ushort* __restrict__ pairBin,
    int* __restrict__ off, uint* __restrict__ rec)
{
    __shared__ uint recS[STAGE_CAP];   // 60 KB
    __shared__ uint lcnt[512];
    __shared__ uint scanSm[512];
    __shared__ uint cur[512];
    int b = blockIdx.x, t = threadIdx.x;
    lcnt[t] = 0;
    __syncthreads();
    int s0 = bukOff[b], s1 = bukOff[b + 1];
    int n = s1 - s0;
    for (int k = t; k < n; k += BF_THREADS)
        atomicAdd(&lcnt[pairBin[s0 + k]], 1u);
    __syncthreads();
    // exclusive scan of 512 counts, 1 per thread (Hillis-Steele, 9 steps)
    uint v = lcnt[t];
    scanSm[t] = v;
    __syncthreads();
    for (int o = 1; o < 512; o <<= 1) {
        uint x = (t >= o) ? scanSm[t - o] : 0;
        __syncthreads();
        scanSm[t] += x;
        __syncthreads();
    }
    uint excl = scanSm[t] - v;
    cur[t] = excl;
    // write CSR offsets for this bucket's real bins (excl is in-register)
    int gbin0, dirEnd;
    if (b < NBUK_I) { gbin0 = b << BUK_SHIFT; dirEnd = N_I; }
    else { gbin0 = N_I + ((b - NBUK_I) << BUK_SHIFT); dirEnd = N_TOTAL; }
    int lim = dirEnd - gbin0; if (lim > 512) lim = 512;
    if (t < lim) off[gbin0 + t] = s0 + (int)excl;
    __syncthreads();   // all cur[] stores visible before placement mutates
    if (n <= STAGE_CAP) {
        for (int k = t; k < n; k += BF_THREADS) {
            uint lbin = pairBin[s0 + k];
            uint r = atomicAdd(&cur[lbin], 1u);
            recS[r] = pairRec[s0 + k];
        }
        __syncthreads();
        for (int k = t; k < n; k += BF_THREADS)   // linear, fully-coalesced
            rec[(size_t)s0 + k] = recS[k];
    } else {
        // exact fallback (never expected at this data scale)
        for (int k = t; k < n; k += BF_THREADS) {
            uint lbin = pairBin[s0 + k];
            uint r = atomicAdd(&cur[lbin], 1u);
            rec[(size_t)s0 + r] = pairRec[s0 + k];
        }
    }
}

// ---------------- phase E: fused gather, ALL slices in one launch -----------
// Round-6: one wave per dst row accumulates across all its slices' spans and
// writes out ONCE — removes the 5 extra launches and ~128 MB of out[]
// accumulate round-trips the per-slice gathers paid.
__global__ __launch_bounds__(256) void gather_all(
    const int* __restrict__ off, const uint* __restrict__ rec,
    const ushort* __restrict__ ue16, const ushort* __restrict__ ie16,
    float* __restrict__ agg_users, float* __restrict__ agg_items)
{
    int gid  = blockIdx.x * blockDim.x + threadIdx.x;
    int row  = gid >> 6;
    int lane = gid & 63;
    if (row >= NUM_ITEMS + NUM_USERS) return;
    const ushort* emb; float* outp; int nspans, bin0, binStride;
    if (row < NUM_ITEMS) {
        emb = ue16; outp = agg_items + (size_t)row * DIM;
        nspans = SLICES_U; bin0 = row; binStride = NUM_ITEMS;
    } else {
        int r = row - NUM_ITEMS;
        emb = ie16; outp = agg_users + (size_t)r * DIM;
        nspans = SLICES_I; bin0 = N_I + r; binStride = NUM_USERS;
    }
    float acc = 0.f;
    for (int sp = 0; sp < nspans; ++sp) {
        int bidx = bin0 + sp * binStride;
        int k = off[bidx];
        int e = off[bidx + 1];
        for (; k + 8 <= e; k += 8) {
            uint r0 = rec[k],   r1 = rec[k+1], r2 = rec[k+2], r3 = rec[k+3];
            uint r4 = rec[k+4], r5 = rec[k+5], r6 = rec[k+6], r7 = rec[k+7];
            ushort b0 = emb[(size_t)(r0 >> 15) * DIM + lane];
            ushort b1 = emb[(size_t)(r1 >> 15) * DIM + lane];
            ushort b2 = emb[(size_t)(r2 >> 15) * DIM + lane];
            ushort b3 = emb[(size_t)(r3 >> 15) * DIM + lane];
            ushort b4 = emb[(size_t)(r4 >> 15) * DIM + lane];
            ushort b5 = emb[(size_t)(r5 >> 15) * DIM + lane];
            ushort b6 = emb[(size_t)(r6 >> 15) * DIM + lane];
            ushort b7 = emb[(size_t)(r7 >> 15) * DIM + lane];
            acc += (float)(r0 & 0x7FFFu) * W_INV * __uint_as_float((uint)b0 << 16);
            acc += (float)(r1 & 0x7FFFu) * W_INV * __uint_as_float((uint)b1 << 16);
            acc += (float)(r2 & 0x7FFFu) * W_INV * __uint_as_float((uint)b2 << 16);
            acc += (float)(r3 & 0x7FFFu) * W_INV * __uint_as_float((uint)b3 << 16);
            acc += (float)(r4 & 0x7FFFu) * W_INV * __uint_as_float((uint)b4 << 16);
            acc += (float)(r5 & 0x7FFFu) * W_INV * __uint_as_float((uint)b5 << 16);
            acc += (float)(r6 & 0x7FFFu) * W_INV * __uint_as_float((uint)b6 << 16);
            acc += (float)(r7 & 0x7FFFu) * W_INV * __uint_as_float((uint)b7 << 16);
        }
        for (; k + 4 <= e; k += 4) {
            uint r0 = rec[k], r1 = rec[k+1], r2 = rec[k+2], r3 = rec[k+3];
            ushort b0 = emb[(size_t)(r0 >> 15) * DIM + lane];
            ushort b1 = emb[(size_t)(r1 >> 15) * DIM + lane];
            ushort b2 = emb[(size_t)(r2 >> 15) * DIM + lane];
            ushort b3 = emb[(size_t)(r3 >> 15) * DIM + lane];
            acc += (float)(r0 & 0x7FFFu) * W_INV * __uint_as_float((uint)b0 << 16);
            acc += (float)(r1 & 0x7FFFu) * W_INV * __uint_as_float((uint)b1 << 16);
            acc += (float)(r2 & 0x7FFFu) * W_INV * __uint_as_float((uint)b2 << 16);
            acc += (float)(r3 & 0x7FFFu) * W_INV * __uint_as_float((uint)b3 << 16);
        }
        for (; k < e; ++k) {
            uint r0 = rec[k];
            ushort b0 = emb[(size_t)(r0 >> 15) * DIM + lane];
            acc += (float)(r0 & 0x7FFFu) * W_INV * __uint_as_float((uint)b0 << 16);
        }
    }
    outp[lane] = acc;
}

// ======================= scan kernels (tier 2/3 only) =======================
__global__ __launch_bounds__(SCAN_THREADS) void scan_block_sums(
    const int* __restrict__ cnt, int* __restrict__ bsum, int n, int chunk)
{
    int b = blockIdx.x, t = threadIdx.x;
    int base = b * chunk;
    int end  = base + chunk < n ? base + chunk : n;
    int tch  = (chunk + SCAN_THREADS - 1) / SCAN_THREADS;
    int s = base + t * tch;
    int e = s + tch < end ? s + tch : end;
    int local = 0;
    for (int i = s; i < e; ++i) local += cnt[i];
    __shared__ int sm[SCAN_THREADS];
    sm[t] = local;
    __syncthreads();
    for (int o = SCAN_THREADS / 2; o > 0; o >>= 1) {
        if (t < o) sm[t] += sm[t + o];
        __syncthreads();
    }
    if (t == 0) bsum[b] = sm[0];
}

__global__ __launch_bounds__(SCAN_NB) void scan_block_offsets(
    const int* __restrict__ bsum, int* __restrict__ boff,
    int* __restrict__ off_end)
{
    int t = threadIdx.x;
    __shared__ int sm[SCAN_NB];
    int v = bsum[t];
    sm[t] = v;
    __syncthreads();
    for (int o = 1; o < SCAN_NB; o <<= 1) {
        int x = (t >= o) ? sm[t - o] : 0;
        __syncthreads();
        sm[t] += x;
        __syncthreads();
    }
    boff[t] = sm[t] - v;
    if (t == SCAN_NB - 1) *off_end = sm[SCAN_NB - 1];
}

__global__ __launch_bounds__(SCAN_THREADS) void scan_local(
    int* __restrict__ cnt, const int* __restrict__ boff, int n, int chunk)
{
    int b = blockIdx.x, t = threadIdx.x;
    int base = b * chunk;
    int end  = base + chunk < n ? base + chunk : n;
    int tch  = (chunk + SCAN_THREADS - 1) / SCAN_THREADS;
    int s = base + t * tch;
    int e = s + tch < end ? s + tch : end;
    int local = 0;
    for (int i = s; i < e; ++i) local += cnt[i];
    __shared__ int sm[SCAN_THREADS];
    sm[t] = local;
    __syncthreads();
    for (int o = 1; o < SCAN_THREADS; o <<= 1) {
        int x = (t >= o) ? sm[t - o] : 0;
        __syncthreads();
        sm[t] += x;
        __syncthreads();
    }
    int run = boff[b] + ((t == 0) ? 0 : sm[t - 1]);
    for (int i = s; i < e; ++i) {
        int c = cnt[i];
        cnt[i] = run;
        run += c;
    }
}

// ======================= exact-CSR fallback tier ============================
__global__ __launch_bounds__(256) void rank_both_exact(
    const int4* __restrict__ u4, const int4* __restrict__ i4,
    int* __restrict__ cnt, int n_i, int su_shift, int si_shift,
    int4* __restrict__ rank_i, int4* __restrict__ rank_u)
{
    int t = blockIdx.x * blockDim.x + threadIdx.x;
    if (t >= NUM_EDGES / 4) return;
    int4 u = u4[t];
    int4 i = i4[t];
    int4 ri, ru;
    ri.x = atomicAdd(&cnt[(u.x >> su_shift) * NUM_ITEMS + i.x], 1);
    ri.y = atomicAdd(&cnt[(u.y >> su_shift) * NUM_ITEMS + i.y], 1);
    ri.z = atomicAdd(&cnt[(u.z >> su_shift) * NUM_ITEMS + i.z], 1);
    ri.w = atomicAdd(&cnt[(u.w >> su_shift) * NUM_ITEMS + i.w], 1);
    ru.x = atomicAdd(&cnt[n_i + (i.x >> si_shift) * NUM_USERS + u.x], 1);
    ru.y = atomicAdd(&cnt[n_i + (i.y >> si_shift) * NUM_USERS + u.y], 1);
    ru.z = atomicAdd(&cnt[n_i + (i.z >> si_shift) * NUM_USERS + u.z], 1);
    ru.w = atomicAdd(&cnt[n_i + (i.w >> si_shift) * NUM_USERS + u.w], 1);
    rank_i[t] = ri;
    rank_u[t] = ru;
}

__global__ __launch_bounds__(256) void scatter_all(
    const int4* __restrict__ u4, const int4* __restrict__ i4,
    const float4* __restrict__ n4,
    const int4* __restrict__ rank_i, const int4* __restrict__ rank_u,
    const int* __restrict__ off, int n_i, int su_shift, int si_shift,
    uint* __restrict__ rec)
{
    int t = blockIdx.x * blockDim.x + threadIdx.x;
    if (t >= NUM_EDGES / 4) return;
    int4   u  = u4[t];
    int4   i  = i4[t];
    float4 n  = n4[t];
    int4   ri = rank_i[t];
    int4   ru = rank_u[t];
    uint w0 = (uint)(n.x * W_SCALE + 0.5f); if (w0 > 32767u) w0 = 32767u;
    uint w1 = (uint)(n.y * W_SCALE + 0.5f); if (w1 > 32767u) w1 = 32767u;
    uint w2 = (uint)(n.z * W_SCALE + 0.5f); if (w2 > 32767u) w2 = 32767u;
    uint w3 = (uint)(n.w * W_SCALE + 0.5f); if (w3 > 32767u) w3 = 32767u;
    int pi0 = off[(u.x >> su_shift) * NUM_ITEMS + i.x] + ri.x;
    int pi1 = off[(u.y >> su_shift) * NUM_ITEMS + i.y] + ri.y;
    int pi2 = off[(u.z >> su_shift) * NUM_ITEMS + i.z] + ri.z;
    int pi3 = off[(u.w >> su_shift) * NUM_ITEMS + i.w] + ri.w;
    int pu0 = off[n_i + (i.x >> si_shift) * NUM_USERS + u.x] + ru.x;
    int pu1 = off[n_i + (i.y >> si_shift) * NUM_USERS + u.y] + ru.y;
    int pu2 = off[n_i + (i.z >> si_shift) * NUM_USERS + u.z] + ru.z;
    int pu3 = off[n_i + (i.w >> si_shift) * NUM_USERS + u.w] + ru.w;
    rec[pi0] = ((uint)u.x << 15) | w0;
    rec[pi1] = ((uint)u.y << 15) | w1;
    rec[pi2] = ((uint)u.z << 15) | w2;
    rec[pi3] = ((uint)u.w << 15) | w3;
    rec[pu0] = ((uint)i.x << 15) | w0;
    rec[pu1] = ((uint)i.y << 15) | w1;
    rec[pu2] = ((uint)i.z << 15) | w2;
    rec[pu3] = ((uint)i.w << 15) | w3;
}

// ---------------- exact-CSR gather (tier 2/3 only) --------------------------
__global__ __launch_bounds__(256) void gather_pass(
    const int* __restrict__ off, int bin_base,
    const uint* __restrict__ rec,
    const ushort* __restrict__ emb16,
    float* __restrict__ out, int nrows, int accumulate)
{
    int gid  = blockIdx.x * blockDim.x + threadIdx.x;
    int row  = gid >> 6;
    int lane = gid & 63;
    if (row >= nrows) return;
    int b = bin_base + row;
    int s = off[b];
    int e = off[b + 1];
    float acc = accumulate ? out[(size_t)row * DIM + lane] : 0.f;
    int k = s;
    for (; k + 8 <= e; k += 8) {
        uint r0 = rec[k],   r1 = rec[k+1], r2 = rec[k+2], r3 = rec[k+3];
        uint r4 = rec[k+4], r5 = rec[k+5], r6 = rec[k+6], r7 = rec[k+7];
        ushort b0 = emb16[(size_t)(r0 >> 15) * DIM + lane];
        ushort b1 = emb16[(size_t)(r1 >> 15) * DIM + lane];
        ushort b2 = emb16[(size_t)(r2 >> 15) * DIM + lane];
        ushort b3 = emb16[(size_t)(r3 >> 15) * DIM + lane];
        ushort b4 = emb16[(size_t)(r4 >> 15) * DIM + lane];
        ushort b5 = emb16[(size_t)(r5 >> 15) * DIM + lane];
        ushort b6 = emb16[(size_t)(r6 >> 15) * DIM + lane];
        ushort b7 = emb16[(size_t)(r7 >> 15) * DIM + lane];
        acc += (float)(r0 & 0x7FFFu) * W_INV * __uint_as_float((uint)b0 << 16);
        acc += (float)(r1 & 0x7FFFu) * W_INV * __uint_as_float((uint)b1 << 16);
        acc += (float)(r2 & 0x7FFFu) * W_INV * __uint_as_float((uint)b2 << 16);
        acc += (float)(r3 & 0x7FFFu) * W_INV * __uint_as_float((uint)b3 << 16);
        acc += (float)(r4 & 0x7FFFu) * W_INV * __uint_as_float((uint)b4 << 16);
        acc += (float)(r5 & 0x7FFFu) * W_INV * __uint_as_float((uint)b5 << 16);
        acc += (float)(r6 & 0x7FFFu) * W_INV * __uint_as_float((uint)b6 << 16);
        acc += (float)(r7 & 0x7FFFu) * W_INV * __uint_as_float((uint)b7 << 16);
    }
    for (; k + 4 <= e; k += 4) {
        uint r0 = rec[k], r1 = rec[k+1], r2 = rec[k+2], r3 = rec[k+3];
        ushort b0 = emb16[(size_t)(r0 >> 15) * DIM + lane];
        ushort b1 = emb16[(size_t)(r1 >> 15) * DIM + lane];
        ushort b2 = emb16[(size_t)(r2 >> 15) * DIM + lane];
        ushort b3 = emb16[(size_t)(r3 >> 15) * DIM + lane];
        acc += (float)(r0 & 0x7FFFu) * W_INV * __uint_as_float((uint)b0 << 16);
        acc += (float)(r1 & 0x7FFFu) * W_INV * __uint_as_float((uint)b1 << 16);
        acc += (float)(r2 & 0x7FFFu) * W_INV * __uint_as_float((uint)b2 << 16);
        acc += (float)(r3 & 0x7FFFu) * W_INV * __uint_as_float((uint)b3 << 16);
    }
    for (; k < e; ++k) {
        uint r0 = rec[k];
        ushort b0 = emb16[(size_t)(r0 >> 15) * DIM + lane];
        acc += (float)(r0 & 0x7FFFu) * W_INV * __uint_as_float((uint)b0 << 16);
    }
    out[(size_t)row * DIM + lane] = acc;
}

extern "C" void kernel_launch(void* const* d_in, const int* in_sizes, int n_in,
                              void* d_out, int out_size, void* d_ws, size_t ws_size,
                              hipStream_t stream) {
    const float* user_emb  = (const float*)d_in[0];
    const float* item_emb  = (const float*)d_in[1];
    const float* edge_norm = (const float*)d_in[2];
    const int*   u_idx     = (const int*)d_in[3];
    const int*   i_idx     = (const int*)d_in[4];

    float* agg_users = (float*)d_out;                        // 100000*64
    float* agg_items = agg_users + (size_t)NUM_USERS * DIM;  // 50000*64

    const int un4 = NUM_USERS * DIM / 4;
    const int in4 = NUM_ITEMS * DIM / 4;
    const int eb4 = (NUM_EDGES / 4 + 255) / 256;
    const int cb  = (un4 + in4 + 255) / 256;
    const size_t bf16_bytes = ((size_t)NUM_USERS + NUM_ITEMS) * DIM * sizeof(ushort);

    // ---------- tier 1: deterministic bucket partition -> local-scan CSR ----
    {
        const size_t off_bytes  = (size_t)(N_TOTAL + 1) * sizeof(int);
        const size_t buk_bytes  = (size_t)(2 * NBUK + 2) * sizeof(int);
        const size_t wgh_bytes  = (size_t)PWG * NBUK * sizeof(ushort);     // 1.5 MB
        const size_t wgp_bytes  = (size_t)NBUK * PWG * sizeof(uint);       // 3.1 MB
        const size_t prec_bytes = (size_t)2 * NUM_EDGES * sizeof(uint);    // 32 MB
        const size_t pbin_bytes = (size_t)2 * NUM_EDGES * sizeof(ushort);  // 16 MB
        const size_t rec_bytes  = (size_t)2 * NUM_EDGES * sizeof(uint);    // 32 MB
        const size_t need = off_bytes + buk_bytes + 64 + wgh_bytes + 64
                          + wgp_bytes + 64 + prec_bytes + 64 + pbin_bytes + 64
                          + rec_bytes + 64 + bf16_bytes + 256;
        if (ws_size >= need) {
            char* p = (char*)d_ws;
            int*    off     = (int*)p;    p += off_bytes;
            int*    bukTot  = (int*)p;    p += (size_t)NBUK * sizeof(int);
            int*    bukOff  = (int*)p;    p += (size_t)(NBUK + 1) * sizeof(int);
            p = (char*)(((uintptr_t)p + 63) & ~(uintptr_t)63);
            ushort* wgHist  = (ushort*)p; p += wgh_bytes;
            p = (char*)(((uintptr_t)p + 63) & ~(uintptr_t)63);
            uint*   wgPrefixT = (uint*)p; p += wgp_bytes;
            p = (char*)(((uintptr_t)p + 63) & ~(uintptr_t)63);
            uint*   pairRec = (uint*)p;   p += prec_bytes;
            p = (char*)(((uintptr_t)p + 63) & ~(uintptr_t)63);
            ushort* pairBin = (ushort*)p; p += pbin_bytes;
            p = (char*)(((uintptr_t)p + 63) & ~(uintptr_t)63);
            uint*   rec     = (uint*)p;   p += rec_bytes;
            p = (char*)(((uintptr_t)p + 63) & ~(uintptr_t)63);
            ushort* ue16    = (ushort*)p; p += (size_t)NUM_USERS * DIM * sizeof(ushort);
            ushort* ie16    = (ushort*)p;

            bucket_hist_conv<<<PWG + cb, 256, 0, stream>>>(
                u_idx, i_idx, wgHist,
                (const float4*)user_emb, (const float4*)item_emb,
                (ushort4*)ue16, (ushort4*)ie16, un4, in4, PWG);
            mscan<<<NBUK, 256, 0, stream>>>(wgHist, wgPrefixT, bukTot);
            bucket_scan<<<1, 256, 0, stream>>>(bukTot, bukOff, off + N_TOTAL);
            partition_pairs<<<PWG, 256, 0, stream>>>(
                u_idx, i_idx, edge_norm, wgHist, wgPrefixT, bukOff,
                pairRec, pairBin);
            bucket_fill<<<NBUK, BF_THREADS, 0, stream>>>(
                bukOff, pairRec, pairBin, off, rec);
            const int grows = NUM_ITEMS + NUM_USERS;
            gather_all<<<((grows * 64) + 255) / 256, 256, 0, stream>>>(
                off, rec, ue16, ie16, agg_users, agg_items);
            return;
        }
    }

    // ---------- tier 2/3: exact CSR via global atomics, sliced or not -------
    {
        const size_t rec_bytes  = (size_t)2 * NUM_EDGES * sizeof(uint);
        const size_t rank_bytes = (size_t)2 * NUM_EDGES * sizeof(int);
        auto need_for = [&](int SU, int SI) -> size_t {
            size_t n_total = (size_t)SU * NUM_ITEMS + (size_t)SI * NUM_USERS;
            size_t off_bytes = (n_total + 1 + 2 * SCAN_NB) * sizeof(int);
            return off_bytes + 64 + rec_bytes + 64 + rank_bytes + 64 + bf16_bytes
                 + 256;
        };
        int SU = 0, SI = 0, su_shift = 17, si_shift = 17;
        if (ws_size >= need_for(SLICES_U, SLICES_I)) {
            SU = SLICES_U; SI = SLICES_I;
            su_shift = SLICE_SHIFT; si_shift = SLICE_SHIFT;
        } else if (ws_size >= need_for(1, 1)) {
            SU = 1; SI = 1;
        }
        if (SU > 0) {
            const int n_i = SU * NUM_ITEMS;
            const int n_u = SI * NUM_USERS;
            const int n_total = n_i + n_u;

            char* p = (char*)d_ws;
            int*   cnt  = (int*)p;   p += (size_t)(n_total + 1) * sizeof(int);
            int*   bsum = (int*)p;   p += (size_t)SCAN_NB * sizeof(int);
            int*   boff = (int*)p;   p += (size_t)SCAN_NB * sizeof(int);
            p = (char*)(((uintptr_t)p + 63) & ~(uintptr_t)63);
            uint*  rec  = (uint*)p;  p += rec_bytes;
            p = (char*)(((uintptr_t)p + 63) & ~(uintptr_t)63);
            int*   rank_i = (int*)p; p += (size_t)NUM_EDGES * sizeof(int);
            int*   rank_u = (int*)p; p += (size_t)NUM_EDGES * sizeof(int);
            p = (char*)(((uintptr_t)p + 63) & ~(uintptr_t)63);
            ushort* ue16 = (ushort*)p; p += (size_t)NUM_USERS * DIM * sizeof(ushort);
            ushort* ie16 = (ushort*)p;

            hipMemsetAsync(cnt, 0, (size_t)(n_total + 1) * sizeof(int), stream);
            convert_both<<<cb, 256, 0, stream>>>(
                (const float4*)user_emb, (const float4*)item_emb,
                (ushort4*)ue16, (ushort4*)ie16, un4, in4);
            rank_both_exact<<<eb4, 256, 0, stream>>>(
                (const int4*)u_idx, (const int4*)i_idx, cnt, n_i,
                su_shift, si_shift, (int4*)rank_i, (int4*)rank_u);
            const int chunk = (n_total + SCAN_NB - 1) / SCAN_NB;
            scan_block_sums<<<SCAN_NB, SCAN_THREADS, 0, stream>>>(
                cnt, bsum, n_total, chunk);
            scan_block_offsets<<<1, SCAN_NB, 0, stream>>>(bsum, boff, cnt + n_total);
            scan_local<<<SCAN_NB, SCAN_THREADS, 0, stream>>>(
                cnt, boff, n_total, chunk);
            scatter_all<<<eb4, 256, 0, stream>>>(
                (const int4*)u_idx, (const int4*)i_idx, (const float4*)edge_norm,
                (const int4*)rank_i, (const int4*)rank_u,
                cnt, n_i, su_shift, si_shift, rec);
            for (int s = 0; s < SU; ++s) {
                gather_pass<<<((NUM_ITEMS * 64) + 255) / 256, 256, 0, stream>>>(
                    cnt, s * NUM_ITEMS, rec, ue16, agg_items, NUM_ITEMS,
                    s > 0 ? 1 : 0);
            }
            for (int s = 0; s < SI; ++s) {
                gather_pass<<<((NUM_USERS * 64) + 255) / 256, 256, 0, stream>>>(
                    cnt, n_i + s * NUM_USERS, rec, ie16, agg_users, NUM_USERS,
                    s > 0 ? 1 : 0);
            }
            return;
        }
    }

    // ---------- tier 4: scatter-atomic ----------
    hipMemsetAsync(d_out, 0, (size_t)out_size * sizeof(float), stream);
    const long long total_threads = (long long)NUM_EDGES * 64;
    const int blocks = (int)((total_threads + 255) / 256);
    lightgcn_scatter<<<blocks, 256, 0, stream>>>(
        user_emb, item_emb, edge_norm, u_idx, i_idx, agg_users, agg_items);
}